// Round 6
// baseline (1600.049 us; speedup 1.0000x reference)
//
#include <hip/hip_runtime.h>
#include <math.h>

// FireflyVQ R6: fp32 VALU path for code-determining GEMMs (down1/down2/e0, proven)
// + split-bf16 MFMA for up1/up2 with N-MAJOR B operands and direct global->reg
// fragments (no LDS, no tr-read, no inline asm). R5 absmax 4.94 isolated the
// tr-read addressing as the gemmS bug; n-major B makes B-fragments contiguous.

using u16 = unsigned short;
typedef __attribute__((ext_vector_type(8))) short bf16x8;
typedef __attribute__((ext_vector_type(8))) u16 u16x8;
typedef __attribute__((ext_vector_type(4))) float f32x4;

constexpr int NQ = 9, CBS = 1024, CBD = 8;
constexpr int TQ = 2048;
constexpr int NTOK = 16384;
#define EPSN 1e-12f

// ---- ws layout (float offsets). Aliased regions are strictly stream-ordered.
constexpr size_t OFF_X1   = 0;                        // x1 fp32 [8][512][4096]
constexpr size_t OFF_US   = OFF_X1;                   // us u16 2x[32768][512] n-major (alias)
constexpr size_t OFF_X2   = OFF_X1 + 16777216;        // x2 fp32 [8][512][2048]
constexpr size_t OFF_ZQS  = OFF_X2;                   // zqs u16 2x[16384][512] n-major (alias)
constexpr size_t OFF_E0T  = OFF_X2 + 8388608;         // e0t [16384][72]
constexpr size_t OFF_Q    = OFF_E0T + 1179648;        // Q [72][16384]
constexpr size_t OFF_UW1S = OFF_Q + 1179648;          // uw1 2 planes x 524288 u16
constexpr size_t OFF_UW2S = OFF_UW1S + 524288;
constexpr size_t OFF_WINN = OFF_UW2S + 524288;        // 36,864
constexpr size_t OFF_WOUT = OFF_WINN + 36864;         // 36,864
constexpr size_t OFF_CBS  = OFF_WOUT + 36864;         // 18,432
constexpr size_t OFF_PT   = OFF_CBS + 18432;          // 2,340
constexpr size_t OFF_BEFF = OFF_PT + 2340;            // 72
constexpr size_t OFF_BSUM = OFF_BEFF + 72;            // 512
constexpr size_t OFF_LOSS = OFF_BSUM + 512;           // 1,024

// ---------------- bf16 helpers ----------------
__device__ __forceinline__ u16 f2bf(float f) {
  unsigned u = __float_as_uint(f);
  u += 0x7FFFu + ((u >> 16) & 1u);
  return (u16)(u >> 16);
}
__device__ __forceinline__ float bf2f(u16 h) { return __uint_as_float(((unsigned)h) << 16); }
__device__ __forceinline__ void split2(float v, u16& a, u16& b) {
  a = f2bf(v); float r = v - bf2f(a);
  b = f2bf(r);
}

// ---------------- prep kernels ----------------

// 2-split planes of ConvTranspose weights: uw[l] A[m=2o+kap][i2] = up_w[l][i2][o][kap]
__global__ void prep_upw(const float* __restrict__ up_w, float* __restrict__ ws) {
  int idx = blockIdx.x * 256 + threadIdx.x;   // [0, 2*524288)
  int mat = idx >> 19, e = idx & 524287;
  int m = e >> 9, i2 = e & 511, o = m >> 1, kap = m & 1;
  float v = up_w[(size_t)mat * 524288 + ((size_t)i2 * 512 + o) * 2 + kap];
  u16* dst = (u16*)(ws + (mat == 0 ? OFF_UW1S : OFF_UW2S));
  u16 s0, s1; split2(v, s0, s1);
  dst[e] = s0; dst[524288 + e] = s1;
}

__global__ void prep_small1(const float* __restrict__ in_v, const float* __restrict__ in_g,
                            const float* __restrict__ out_v, const float* __restrict__ out_g,
                            const float* __restrict__ out_b, const float* __restrict__ codebooks,
                            float* __restrict__ ws) {
  int bid = blockIdx.x, tid = threadIdx.x;
  if (bid < 18) {  // WinN: 72 rows, one wave each
    int wid = bid * 4 + (tid >> 6), lane = tid & 63;
    if (wid < 72) {
      const float* v = in_v + (size_t)wid * 512;
      float ss = 0.f;
      for (int c = lane; c < 512; c += 64) ss += v[c] * v[c];
      #pragma unroll
      for (int o = 32; o; o >>= 1) ss += __shfl_xor(ss, o);
      float sc = in_g[wid] / sqrtf(ss);
      float* dst = ws + OFF_WINN + (size_t)wid * 512;
      for (int c = lane; c < 512; c += 64) dst[c] = v[c] * sc;
    }
  } else if (bid < 36) {  // WoutS: 4608 rows of 8 -> [c][i*8+d]
    int r = (bid - 18) * 256 + tid;
    if (r < 4608) {
      int i = r >> 9, c = r & 511;
      const float* v = out_v + (size_t)r * 8;
      float ss = 0.f;
      #pragma unroll
      for (int d = 0; d < 8; d++) ss += v[d] * v[d];
      float sc = out_g[r] / sqrtf(ss);
      float* dst = ws + OFF_WOUT + (size_t)c * 72 + i * 8;
      #pragma unroll
      for (int d = 0; d < 8; d++) dst[d] = v[d] * sc;
    }
  } else if (bid < 72) {  // codebook scalars
    int r = (bid - 36) * 256 + tid;
    if (r < 9216) {
      int i = r >> 10, j = r & 1023;
      const float* v = codebooks + (size_t)r * 8;
      float ss = 0.f;
      #pragma unroll
      for (int d = 0; d < 8; d++) ss += v[d] * v[d];
      float nm = fmaxf(sqrtf(ss), EPSN);
      float nsq = 0.f;
      #pragma unroll
      for (int d = 0; d < 8; d++) { float cn = v[d] / nm; nsq += cn * cn; }
      ws[OFF_CBS + ((size_t)i * 2 + 0) * 1024 + j] = 2.0f / nm;
      ws[OFF_CBS + ((size_t)i * 2 + 1) * 1024 + j] = nsq;
    }
  } else {  // bias sum
    int c = (bid - 72) * 256 + tid;
    if (c < 512) {
      float s = 0.f;
      #pragma unroll
      for (int j = 0; j < 9; j++) s += out_b[j * 512 + c];
      ws[OFF_BSUM + c] = s;
    }
  }
}

__global__ void prep2(const float* __restrict__ in_b, const float* __restrict__ out_b,
                      float* __restrict__ ws) {
  int gw = blockIdx.x * 4 + (threadIdx.x >> 6), lane = threadIdx.x & 63;
  const float* WinN = ws + OFF_WINN;
  const float* WoutS = ws + OFF_WOUT;
  if (gw < 2304) {  // P tri blocks, row stride 65
    int tri = gw >> 6, dd = gw & 63;
    int ip = 1;
    while (tri >= ip * (ip + 1) / 2) ip++;
    int i = tri - ip * (ip - 1) / 2;
    int d = dd >> 3, dp = dd & 7;
    const float* a = WinN + (size_t)(ip * 8 + d) * 512;
    float s = 0.f;
    for (int c = lane; c < 512; c += 64) s += a[c] * WoutS[(size_t)c * 72 + i * 8 + dp];
    #pragma unroll
    for (int o = 32; o; o >>= 1) s += __shfl_xor(s, o);
    if (lane == 0) ws[OFF_PT + (size_t)tri * 65 + dd] = s;
  } else if (gw < 2376) {  // beff
    int r = gw - 2304;
    int i = r >> 3;
    const float* a = WinN + (size_t)r * 512;
    float s = 0.f;
    for (int c = lane; c < 512; c += 64) {
      float ob = 0.f;
      for (int j = 0; j < i; j++) ob += out_b[j * 512 + c];
      s += a[c] * ob;
    }
    #pragma unroll
    for (int o = 32; o; o >>= 1) s += __shfl_xor(s, o);
    if (lane == 0) ws[OFF_BEFF + r] = in_b[r] - s;
  }
}

// ---------------- proven fp32 tiled GEMM (R2 verbatim) ----------------
// GATHER: 0=DOWN (stride-2 conv gather), 1=BT (per-b [k][Tt])
// SCATTER: 0=NORM ([b][m][Tt]), 1=E0T ([n][M])
template <int GATHER, int SCATTER>
__global__ __launch_bounds__(256) void gemm_conv(const float* __restrict__ A,
                                                 const float* __restrict__ Bsrc,
                                                 const float* __restrict__ bias,
                                                 float* __restrict__ Out,
                                                 int M, int K, int N, int Tt) {
  constexpr int BM = 128, BN = 128, BK = 16;
  __shared__ float As[BK][BM + 4];
  __shared__ float Bs[BK][BN + 4];
  int tid = threadIdx.x;
  int tx = tid & 15, ty = tid >> 4;
  int n0 = blockIdx.x * BN, m0 = blockIdx.y * BM;
  int b = n0 / Tt, t0 = n0 % Tt;
  float acc[8][8];
  #pragma unroll
  for (int i = 0; i < 8; i++)
    #pragma unroll
    for (int j = 0; j < 8; j++) acc[i][j] = 0.f;

  for (int k0 = 0; k0 < K; k0 += BK) {
    #pragma unroll
    for (int rep = 0; rep < 2; rep++) {
      int f = tid + rep * 256;
      int row = f >> 2, c4 = (f & 3) << 2;
      int m = m0 + row, k = k0 + c4;
      float4 v = make_float4(0.f, 0.f, 0.f, 0.f);
      if (m < M) {
        if (k + 3 < K) {
          v = *(const float4*)(A + (size_t)m * K + k);
        } else {
          float tmp[4] = {0.f, 0.f, 0.f, 0.f};
          for (int c = 0; c < 4; c++)
            if (k + c < K) tmp[c] = A[(size_t)m * K + k + c];
          v = make_float4(tmp[0], tmp[1], tmp[2], tmp[3]);
        }
      }
      As[c4 + 0][row] = v.x; As[c4 + 1][row] = v.y;
      As[c4 + 2][row] = v.z; As[c4 + 3][row] = v.w;
    }
    #pragma unroll
    for (int rep = 0; rep < 2; rep++) {
      int f = tid + rep * 256;
      int kk = f >> 5, n4 = (f & 31) << 2;
      int k = k0 + kk;
      float4 v;
      if (GATHER == 0) {
        int ich = k >> 1, k2 = k & 1;
        const float* p = Bsrc + ((size_t)(b * (K >> 1) + ich)) * (2 * Tt) + 2 * (t0 + n4);
        float4 lo = *(const float4*)p;
        float4 hi = *(const float4*)(p + 4);
        v = k2 ? make_float4(lo.y, lo.w, hi.y, hi.w) : make_float4(lo.x, lo.z, hi.x, hi.z);
      } else {
        v = *(const float4*)(Bsrc + ((size_t)(b * K + k)) * Tt + t0 + n4);
      }
      *(float4*)&Bs[kk][n4] = v;
    }
    __syncthreads();
    #pragma unroll
    for (int kk = 0; kk < BK; kk++) {
      float a[8], bb[8];
      *(float4*)&a[0] = *(float4*)&As[kk][ty * 8];
      *(float4*)&a[4] = *(float4*)&As[kk][ty * 8 + 4];
      *(float4*)&bb[0] = *(float4*)&Bs[kk][tx * 8];
      *(float4*)&bb[4] = *(float4*)&Bs[kk][tx * 8 + 4];
      #pragma unroll
      for (int i = 0; i < 8; i++)
        #pragma unroll
        for (int j = 0; j < 8; j++) acc[i][j] = fmaf(a[i], bb[j], acc[i][j]);
    }
    __syncthreads();
  }
  if (SCATTER == 0) {
    #pragma unroll
    for (int i = 0; i < 8; i++) {
      int m = m0 + ty * 8 + i;
      if (m < M) {
        float bv = bias ? bias[m] : 0.f;
        float* p = Out + ((size_t)(b * M + m)) * Tt + t0 + tx * 8;
        *(float4*)p = make_float4(acc[i][0] + bv, acc[i][1] + bv, acc[i][2] + bv, acc[i][3] + bv);
        *(float4*)(p + 4) = make_float4(acc[i][4] + bv, acc[i][5] + bv, acc[i][6] + bv, acc[i][7] + bv);
      }
    }
  } else {
    #pragma unroll
    for (int j = 0; j < 8; j++) {
      int n = n0 + tx * 8 + j;
      int m = m0 + ty * 8;
      if (m < M) {
        float* p = Out + (size_t)n * M + m;
        if (m + 7 < M) {
          *(float4*)p = make_float4(acc[0][j], acc[1][j], acc[2][j], acc[3][j]);
          *(float4*)(p + 4) = make_float4(acc[4][j], acc[5][j], acc[6][j], acc[7][j]);
        } else {
          for (int i = 0; i < 8 && m + i < M; i++) p[i] = acc[i][j];
        }
      }
    }
  }
}

// ---------------- split-bf16 MFMA GEMM, n-major B, no LDS ----------------
// C[m][n] = sum A_p B_q (p+q<=NS-1). Tile 128(m) x 64(n), 4 waves (2x2), BK=32.
// A planes: k-major [M][K] u16. B planes: n-major [N][K] u16.
// A-frag (lane l): row=l&15, k=(l>>4)*8+j  -> contiguous 16B at A[row][k0+g*8]
// B-frag (lane l): col=l&15, k=(l>>4)*8+j  -> contiguous 16B at B[col][k0+g*8]
// C-frag: col=lane&15 (n), row=(lane>>4)*4+reg (m)   [m89-verified]
// EPI: 3 = up1 -> us n-major u16 2-split [tau(32768)][o(512)], tau=b*4096+2t+kap
//      4 = up2 final -> x fp32 [b][512][8192]
template <int NS, int EPI>
__global__ __launch_bounds__(256) void gemmS(const u16* __restrict__ Asp,
                                             const u16* __restrict__ Bnm,
                                             const float* __restrict__ bias,
                                             float* __restrict__ OutF,
                                             u16* __restrict__ OutS,
                                             int K, int N, int aStride, int bStride) {
  const int tid = threadIdx.x;
  const int w = tid >> 6, l = tid & 63;
  const int g = l >> 4, li = l & 15;
  const int wr = w >> 1, wc = w & 1;
  const int n0 = blockIdx.x * 64, m0 = blockIdx.y * 128;

  f32x4 acc[4][2];
  #pragma unroll
  for (int a = 0; a < 4; a++)
    #pragma unroll
    for (int b = 0; b < 2; b++) acc[a][b] = (f32x4){0.f, 0.f, 0.f, 0.f};

  const u16* Arow = Asp + (size_t)(m0 + wr * 64 + li) * K + g * 8;  // + fm*16*K + p*aStride + k0
  const u16* Brow = Bnm + (size_t)(n0 + wc * 32 + li) * K + g * 8;  // + fn*16*K + q*bStride + k0

  for (int k0 = 0; k0 < K; k0 += 32) {
    bf16x8 bfr[2][NS];
    #pragma unroll
    for (int fn = 0; fn < 2; ++fn)
      #pragma unroll
      for (int q = 0; q < NS; ++q)
        bfr[fn][q] = *(const bf16x8*)(Brow + (size_t)q * bStride + (size_t)fn * 16 * K + k0);
    #pragma unroll
    for (int fm = 0; fm < 4; ++fm) {
      bf16x8 afr[NS];
      #pragma unroll
      for (int p = 0; p < NS; ++p)
        afr[p] = *(const bf16x8*)(Arow + (size_t)p * aStride + (size_t)fm * 16 * K + k0);
      #pragma unroll
      for (int fn = 0; fn < 2; ++fn) {
        f32x4 a = acc[fm][fn];
        a = __builtin_amdgcn_mfma_f32_16x16x32_bf16(afr[0], bfr[fn][0], a, 0, 0, 0);
        a = __builtin_amdgcn_mfma_f32_16x16x32_bf16(afr[1], bfr[fn][0], a, 0, 0, 0);
        a = __builtin_amdgcn_mfma_f32_16x16x32_bf16(afr[0], bfr[fn][1], a, 0, 0, 0);
        if constexpr (NS == 3) {
          a = __builtin_amdgcn_mfma_f32_16x16x32_bf16(afr[2], bfr[fn][0], a, 0, 0, 0);
          a = __builtin_amdgcn_mfma_f32_16x16x32_bf16(afr[1], bfr[fn][1], a, 0, 0, 0);
          a = __builtin_amdgcn_mfma_f32_16x16x32_bf16(afr[0], bfr[fn][2], a, 0, 0, 0);
        }
        acc[fm][fn] = a;
      }
    }
  }

  const int mbase = m0 + wr * 64 + g * 4;
  const int nbase = n0 + wc * 32 + li;
  if constexpr (EPI == 3) {
    // rows mm = mbase+fm*16+r: r=0->(o0,kap0) r=1->(o0,kap1) r=2->(o0+1,kap0) r=3->(o0+1,kap1)
    #pragma unroll
    for (int fm = 0; fm < 4; ++fm)
      #pragma unroll
      for (int fn = 0; fn < 2; ++fn) {
        int n = nbase + fn * 16;                                   // token 0..16383
        size_t r0 = ((size_t)(n >> 11) * 4096 + 2 * (n & 2047)) * 512;  // row tau0 * 512
        int o0 = (mbase + fm * 16) >> 1;                            // even
        float bv0 = bias[o0], bv1 = bias[o0 + 1];
        u16 a0, a1, c0, c1, e0, e1, h0, h1;
        split2(acc[fm][fn][0] + bv0, a0, a1);  // (o0,   kap0)
        split2(acc[fm][fn][1] + bv0, e0, e1);  // (o0,   kap1)
        split2(acc[fm][fn][2] + bv1, c0, c1);  // (o0+1, kap0)
        split2(acc[fm][fn][3] + bv1, h0, h1);  // (o0+1, kap1)
        *(unsigned*)&OutS[r0 + o0] = (unsigned)a0 | ((unsigned)c0 << 16);
        *(unsigned*)&OutS[r0 + 512 + o0] = (unsigned)e0 | ((unsigned)h0 << 16);
        *(unsigned*)&OutS[16777216u + r0 + o0] = (unsigned)a1 | ((unsigned)c1 << 16);
        *(unsigned*)&OutS[16777216u + r0 + 512 + o0] = (unsigned)e1 | ((unsigned)h1 << 16);
      }
  } else {  // EPI 4 final: x[b][o][2t2+kap]
    #pragma unroll
    for (int fm = 0; fm < 4; ++fm)
      #pragma unroll
      for (int fn = 0; fn < 2; ++fn) {
        int n = nbase + fn * 16;
        int b = n >> 12, t2 = n & 4095;
        #pragma unroll
        for (int rp = 0; rp < 2; ++rp) {
          int mm = mbase + fm * 16 + 2 * rp;
          int o = mm >> 1;
          float bv = bias[o];
          float2 st = make_float2(acc[fm][fn][2 * rp] + bv, acc[fm][fn][2 * rp + 1] + bv);
          *(float2*)&OutF[((size_t)(b * 512 + o)) * 8192 + 2 * t2] = st;
        }
      }
  }
}

// ---------------- zq: fp32 GEMM (K=72), 2-split N-MAJOR u16 output ----------------
__global__ __launch_bounds__(256) void gemm_zq(const float* __restrict__ A,     // WoutS [512][72]
                                               const float* __restrict__ Bsrc,  // Q [72][16384]
                                               const float* __restrict__ bsum,
                                               u16* __restrict__ zqs) {         // [2][16384][512]
  constexpr int K = 72, N = 16384;
  __shared__ float Ash[16][128 + 4];
  __shared__ float Bsh[16][128 + 4];
  int tid = threadIdx.x;
  int tx = tid & 15, ty = tid >> 4;
  int n0 = blockIdx.x * 128, m0 = blockIdx.y * 128;
  float acc[8][8];
  #pragma unroll
  for (int i = 0; i < 8; i++)
    #pragma unroll
    for (int j = 0; j < 8; j++) acc[i][j] = 0.f;

  for (int k0 = 0; k0 < K; k0 += 16) {
    #pragma unroll
    for (int rep = 0; rep < 2; rep++) {
      int f = tid + rep * 256;
      int row = f >> 2, c4 = (f & 3) << 2;
      int m = m0 + row, k = k0 + c4;
      float4 v = make_float4(0.f, 0.f, 0.f, 0.f);
      if (k + 3 < K) v = *(const float4*)(A + (size_t)m * K + k);
      else {
        float tmp[4] = {0.f, 0.f, 0.f, 0.f};
        for (int c = 0; c < 4; c++) if (k + c < K) tmp[c] = A[(size_t)m * K + k + c];
        v = make_float4(tmp[0], tmp[1], tmp[2], tmp[3]);
      }
      Ash[c4 + 0][row] = v.x; Ash[c4 + 1][row] = v.y;
      Ash[c4 + 2][row] = v.z; Ash[c4 + 3][row] = v.w;
    }
    #pragma unroll
    for (int rep = 0; rep < 2; rep++) {
      int f = tid + rep * 256;
      int kk = f >> 5, n4 = (f & 31) << 2;
      int k = k0 + kk;
      float4 v = make_float4(0.f, 0.f, 0.f, 0.f);
      if (k < K) v = *(const float4*)(Bsrc + (size_t)k * N + n0 + n4);
      *(float4*)&Bsh[kk][n4] = v;
    }
    __syncthreads();
    #pragma unroll
    for (int kk = 0; kk < 16; kk++) {
      float a[8], bb[8];
      *(float4*)&a[0] = *(float4*)&Ash[kk][ty * 8];
      *(float4*)&a[4] = *(float4*)&Ash[kk][ty * 8 + 4];
      *(float4*)&bb[0] = *(float4*)&Bsh[kk][tx * 8];
      *(float4*)&bb[4] = *(float4*)&Bsh[kk][tx * 8 + 4];
      #pragma unroll
      for (int i = 0; i < 8; i++)
        #pragma unroll
        for (int j = 0; j < 8; j++) acc[i][j] = fmaf(a[i], bb[j], acc[i][j]);
    }
    __syncthreads();
  }
  // n-major transpose store: for each of 8 tokens, 8 contiguous channels
  #pragma unroll
  for (int j = 0; j < 8; j++) {
    int n = n0 + tx * 8 + j;
    u16x8 q0, q1;
    #pragma unroll
    for (int i = 0; i < 8; i++) {
      u16 a, b; split2(acc[i][j] + bsum[m0 + ty * 8 + i], a, b);
      q0[i] = a; q1[i] = b;
    }
    *(u16x8*)&zqs[(size_t)n * 512 + m0 + ty * 8] = q0;
    *(u16x8*)&zqs[8388608u + (size_t)n * 512 + m0 + ty * 8] = q1;
  }
}

// ---------------- RVQ core (proven) ----------------
__global__ __launch_bounds__(256) void rvq_kernel(const float* __restrict__ codebooks,
                                                  const float* __restrict__ e0t,
                                                  const float* __restrict__ cbsW,
                                                  const float* __restrict__ ptW,
                                                  const float* __restrict__ beffW,
                                                  float* __restrict__ Qout,
                                                  float* __restrict__ codesOut,
                                                  float* __restrict__ lossPart) {
  __shared__ float cbv[8][1024];
  __shared__ float cbs2[2][1024];
  __shared__ float Pt[36 * 65];
  __shared__ float est[16][72];
  __shared__ float lred[4];
  int tid = threadIdx.x, wid = tid >> 6, lane = tid & 63;
  int nb0 = blockIdx.x * 16;
  for (int idx = tid; idx < 2340; idx += 256) Pt[idx] = ptW[idx];
  for (int idx = tid; idx < 16 * 72; idx += 256)
    est[idx / 72][idx % 72] = e0t[(size_t)nb0 * 72 + idx] + beffW[idx % 72];
  float lossLocal = 0.f;

  for (int i = 0; i < NQ; i++) {
    __syncthreads();
    const float* cbg = codebooks + (size_t)i * CBS * CBD;
    for (int lin = tid; lin < 2048; lin += 256) {
      int j = lin >> 1, half = (lin & 1) << 2;
      float4 v = *(const float4*)(cbg + (size_t)j * 8 + half);
      cbv[half + 0][j] = v.x; cbv[half + 1][j] = v.y;
      cbv[half + 2][j] = v.z; cbv[half + 3][j] = v.w;
    }
    for (int lin = tid; lin < 1024; lin += 256) {
      cbs2[0][lin] = cbsW[((size_t)i * 2 + 0) * 1024 + lin];
      cbs2[1][lin] = cbsW[((size_t)i * 2 + 1) * 1024 + lin];
    }
    __syncthreads();

    float ze[4][8], en[4][8];
    #pragma unroll
    for (int w = 0; w < 4; w++) {
      int tokl = wid * 4 + w;
      float ss = 0.f;
      #pragma unroll
      for (int d = 0; d < 8; d++) { float v = est[tokl][i * 8 + d]; ze[w][d] = v; ss += v * v; }
      float inv = 1.0f / fmaxf(sqrtf(ss), EPSN);
      #pragma unroll
      for (int d = 0; d < 8; d++) en[w][d] = ze[w][d] * inv;
    }
    float best[4]; int bidx[4];
    #pragma unroll
    for (int w = 0; w < 4; w++) { best[w] = -INFINITY; bidx[w] = 0; }
    #pragma unroll 4
    for (int r = 0; r < 16; r++) {
      int j = lane + (r << 6);
      float c0 = cbv[0][j], c1 = cbv[1][j], c2 = cbv[2][j], c3 = cbv[3][j];
      float c4 = cbv[4][j], c5 = cbv[5][j], c6 = cbv[6][j], c7 = cbv[7][j];
      float ti = cbs2[0][j], ns = cbs2[1][j];
      #pragma unroll
      for (int w = 0; w < 4; w++) {
        float dt = en[w][0] * c0;
        dt = fmaf(en[w][1], c1, dt); dt = fmaf(en[w][2], c2, dt);
        dt = fmaf(en[w][3], c3, dt); dt = fmaf(en[w][4], c4, dt);
        dt = fmaf(en[w][5], c5, dt); dt = fmaf(en[w][6], c6, dt);
        dt = fmaf(en[w][7], c7, dt);
        float s = fmaf(dt, ti, -ns);
        if (s > best[w]) { best[w] = s; bidx[w] = j; }
      }
    }
    #pragma unroll
    for (int w = 0; w < 4; w++) {
      #pragma unroll
      for (int off = 32; off; off >>= 1) {
        float so = __shfl_xor(best[w], off);
        int jo = __shfl_xor(bidx[w], off);
        if (so > best[w] || (so == best[w] && jo < bidx[w])) { best[w] = so; bidx[w] = jo; }
      }
    }
    int d = lane & 7;
    #pragma unroll
    for (int w = 0; w < 4; w++) {
      int jstar = bidx[w];
      int tokl = wid * 4 + w;
      int n = nb0 + tokl;
      float qd = cbv[d][jstar];
      float diff = ze[w][d] - qd;
      float sq = diff * diff;
      sq += __shfl_xor(sq, 1); sq += __shfl_xor(sq, 2); sq += __shfl_xor(sq, 4);
      if (lane == 0) lossLocal += sq;
      if (lane < 8) Qout[(size_t)(i * 8 + lane) * NTOK + n] = qd;
      if (lane == 0) codesOut[(size_t)((n >> 11) * NQ + i) * TQ + (n & (TQ - 1))] = (float)jstar;
      if (i < NQ - 1) {
        int f = lane >> 3, d2 = lane & 7;
        int ip = i + 1 + f;
        if (ip < NQ) {
          int tri = (ip * (ip - 1)) / 2 + i;
          const float* prow = &Pt[tri * 65 + d2 * 8];
          float s = 0.f;
          #pragma unroll
          for (int dp = 0; dp < 8; dp++) s = fmaf(prow[dp], cbv[dp][jstar], s);
          est[tokl][ip * 8 + d2] -= s;
        }
      }
    }
  }
  if (lane == 0) lred[wid] = lossLocal;
  __syncthreads();
  if (tid == 0) {
    float s = ((lred[0] + lred[1]) + lred[2]) + lred[3];
    lossPart[blockIdx.x] = s;
  }
}

__global__ void loss_fin(const float* __restrict__ lossPart, float* __restrict__ out) {
  __shared__ float s[256];
  int tid = threadIdx.x;
  float v = 0.f;
  for (int r = 0; r < 4; r++) v += lossPart[tid + r * 256];
  s[tid] = v;
  __syncthreads();
  for (int w = 128; w; w >>= 1) {
    if (tid < w) s[tid] += s[tid + w];
    __syncthreads();
  }
  if (tid == 0) {
    float total = s[0] / 131072.0f;
    out[0] = total;
    out[1] = total;
  }
}

// ---------------- launch ----------------
extern "C" void kernel_launch(void* const* d_in, const int* in_sizes, int n_in,
                              void* d_out, int out_size, void* d_ws, size_t ws_size,
                              hipStream_t stream) {
  const float* z      = (const float*)d_in[0];
  const float* down_w = (const float*)d_in[1];
  const float* down_b = (const float*)d_in[2];
  const float* up_w   = (const float*)d_in[3];
  const float* up_b   = (const float*)d_in[4];
  const float* in_v   = (const float*)d_in[5];
  const float* in_g   = (const float*)d_in[6];
  const float* in_b   = (const float*)d_in[7];
  const float* out_v  = (const float*)d_in[8];
  const float* out_g  = (const float*)d_in[9];
  const float* out_b  = (const float*)d_in[10];
  const float* codebooks = (const float*)d_in[11];
  float* ws = (float*)d_ws;
  float* xout = (float*)d_out;
  float* codesOut = xout + (size_t)8 * 512 * 8192;
  float* lossOut = codesOut + (size_t)8 * NQ * TQ;

  hipLaunchKernelGGL(prep_upw, dim3(4096), dim3(256), 0, stream, up_w, ws);
  hipLaunchKernelGGL(prep_small1, dim3(74), dim3(256), 0, stream,
                     in_v, in_g, out_v, out_g, out_b, codebooks, ws);
  hipLaunchKernelGGL(prep2, dim3(594), dim3(256), 0, stream, in_b, out_b, ws);
  // down1 (fp32): [512,1024] @ gathered z -> x1 [8,512,4096]
  hipLaunchKernelGGL((gemm_conv<0, 0>), dim3(256, 4), dim3(256), 0, stream,
                     down_w, z, down_b, ws + OFF_X1, 512, 1024, 32768, 4096);
  // down2 (fp32) -> x2 [8,512,2048]
  hipLaunchKernelGGL((gemm_conv<0, 0>), dim3(128, 4), dim3(256), 0, stream,
                     down_w + 524288, ws + OFF_X1, down_b + 512, ws + OFF_X2, 512, 1024, 16384, 2048);
  // e0 (fp32) = WinN[72,512] @ x2 -> e0t [16384][72]
  hipLaunchKernelGGL((gemm_conv<1, 1>), dim3(128, 1), dim3(256), 0, stream,
                     ws + OFF_WINN, ws + OFF_X2, (const float*)nullptr, ws + OFF_E0T, 72, 512, 16384, 2048);
  // RVQ
  hipLaunchKernelGGL(rvq_kernel, dim3(1024), dim3(256), 0, stream,
                     codebooks, ws + OFF_E0T, ws + OFF_CBS, ws + OFF_PT, ws + OFF_BEFF,
                     ws + OFF_Q, codesOut, ws + OFF_LOSS);
  // zq (fp32, K=72) -> n-major 2-split zqs [2][16384][512]
  hipLaunchKernelGGL(gemm_zq, dim3(128, 4), dim3(256), 0, stream,
                     ws + OFF_WOUT, ws + OFF_Q, ws + OFF_BSUM, (u16*)(ws + OFF_ZQS));
  // up1 (MFMA 2-split): A=uw1s [1024][512], B=zqs n-major -> us n-major [2][32768][512]
  hipLaunchKernelGGL((gemmS<2, 3>), dim3(256, 8), dim3(256), 0, stream,
                     (const u16*)(ws + OFF_UW1S), (const u16*)(ws + OFF_ZQS), up_b,
                     (float*)nullptr, (u16*)(ws + OFF_US), 512, 16384, 524288, 8388608);
  // up2 (MFMA 2-split): A=uw2s, B=us n-major -> x fp32 to d_out
  hipLaunchKernelGGL((gemmS<2, 4>), dim3(512, 8), dim3(256), 0, stream,
                     (const u16*)(ws + OFF_UW2S), (const u16*)(ws + OFF_US), up_b + 512,
                     xout, (u16*)nullptr, 512, 32768, 524288, 16777216);
  hipLaunchKernelGGL(loss_fin, dim3(1), dim3(256), 0, stream, ws + OFF_LOSS, lossOut);
}

// Round 8
// 1316.296 us; speedup vs baseline: 1.2156x; 1.2156x over previous
//
#include <hip/hip_runtime.h>
#include <math.h>

// FireflyVQ R7: all big GEMMs on MFMA via in-register truncation bf16-splits.
// down1/down2 = 3-split (6 passes, fp32-class error, code-safe); up1/up2 = 2-split.
// B staged fp32 in padded LDS (2-way free), A direct-global fp32; split in reg.
// e0/zq fp32 gemm_conv (proven); RVQ unchanged.

using u16 = unsigned short;
typedef __attribute__((ext_vector_type(8))) short bf16x8;
typedef __attribute__((ext_vector_type(4))) float f32x4;

constexpr int NQ = 9, CBS = 1024, CBD = 8;
constexpr int TQ = 2048;
constexpr int NTOK = 16384;
#define EPSN 1e-12f

// ---- ws layout (float offsets); aliases strictly stream-ordered. ~113.4 MiB
constexpr size_t OFF_X1   = 0;                        // x1 [8][512][4096]; later u1f [1024][16384]
constexpr size_t OFF_U1F  = OFF_X1;
constexpr size_t OFF_X2   = OFF_X1 + 16777216;        // x2 [8][512][2048]; later zqf [512][16384]
constexpr size_t OFF_ZQF  = OFF_X2;
constexpr size_t OFF_E0T  = OFF_X2 + 8388608;         // 1,179,648
constexpr size_t OFF_Q    = OFF_E0T + 1179648;        // 1,179,648
constexpr size_t OFF_DWF  = OFF_Q + 1179648;          // 1,048,576 (2x [512][1024])
constexpr size_t OFF_UWF  = OFF_DWF + 1048576;        // 1,048,576 (2x [1024][512])
constexpr size_t OFF_WINN = OFF_UWF + 1048576;        // 36,864
constexpr size_t OFF_WOUT = OFF_WINN + 36864;         // 36,864
constexpr size_t OFF_CBS  = OFF_WOUT + 36864;         // 18,432
constexpr size_t OFF_PT   = OFF_CBS + 18432;          // 2,340
constexpr size_t OFF_BEFF = OFF_PT + 2340;            // 72
constexpr size_t OFF_BSUM = OFF_BEFF + 72;            // 512
constexpr size_t OFF_LOSS = OFF_BSUM + 512;           // 1,024

// ---------------- truncation split: fp32 -> NS bf16 planes ----------------
template <int NS>
__device__ __forceinline__ void tsplit(const float* __restrict__ v, bf16x8* __restrict__ f) {
  #pragma unroll
  for (int j = 0; j < 8; ++j) {
    unsigned u = __float_as_uint(v[j]);
    f[0][j] = (short)(u >> 16);
    if constexpr (NS >= 2) {
      float r = v[j] - __uint_as_float(u & 0xFFFF0000u);
      unsigned ur = __float_as_uint(r);
      f[1][j] = (short)(ur >> 16);
      if constexpr (NS == 3) {
        float r2 = r - __uint_as_float(ur & 0xFFFF0000u);
        f[2][j] = (short)(__float_as_uint(r2) >> 16);
      }
    }
  }
}

template <int NS>
__device__ __forceinline__ f32x4 mmaN(const bf16x8* a, const bf16x8* b, f32x4 acc) {
  if constexpr (NS == 3) {  // smallest terms first
    acc = __builtin_amdgcn_mfma_f32_16x16x32_bf16(a[2], b[0], acc, 0, 0, 0);
    acc = __builtin_amdgcn_mfma_f32_16x16x32_bf16(a[1], b[1], acc, 0, 0, 0);
    acc = __builtin_amdgcn_mfma_f32_16x16x32_bf16(a[0], b[2], acc, 0, 0, 0);
    acc = __builtin_amdgcn_mfma_f32_16x16x32_bf16(a[1], b[0], acc, 0, 0, 0);
    acc = __builtin_amdgcn_mfma_f32_16x16x32_bf16(a[0], b[1], acc, 0, 0, 0);
    acc = __builtin_amdgcn_mfma_f32_16x16x32_bf16(a[0], b[0], acc, 0, 0, 0);
  } else {
    acc = __builtin_amdgcn_mfma_f32_16x16x32_bf16(a[1], b[0], acc, 0, 0, 0);
    acc = __builtin_amdgcn_mfma_f32_16x16x32_bf16(a[0], b[1], acc, 0, 0, 0);
    acc = __builtin_amdgcn_mfma_f32_16x16x32_bf16(a[0], b[0], acc, 0, 0, 0);
  }
  return acc;
}

// ---------------- prep: weights fp32 reorder ----------------
__global__ void prep_wf(const float* __restrict__ down_w, const float* __restrict__ up_w,
                        float* __restrict__ ws) {
  int idx = blockIdx.x * 256 + threadIdx.x;   // [0, 4*524288)
  int mat = idx >> 19, e = idx & 524287;
  if (mat < 2) {  // dwf[l][o][k = kap*512 + i]
    int o = e >> 10, k = e & 1023, kap = k >> 9, i = k & 511;
    ws[OFF_DWF + (size_t)mat * 524288 + e] =
        down_w[((size_t)(mat * 512 + o) * 512 + i) * 2 + kap];
  } else {        // uwf[l][m = 2*out + kap][c = in]
    int m = e >> 9, c = e & 511;
    ws[OFF_UWF + (size_t)(mat - 2) * 524288 + e] =
        up_w[(size_t)(mat - 2) * 524288 + ((size_t)c * 512 + (m >> 1)) * 2 + (m & 1)];
  }
}

__global__ void prep_small1(const float* __restrict__ in_v, const float* __restrict__ in_g,
                            const float* __restrict__ out_v, const float* __restrict__ out_g,
                            const float* __restrict__ out_b, const float* __restrict__ codebooks,
                            float* __restrict__ ws) {
  int bid = blockIdx.x, tid = threadIdx.x;
  if (bid < 18) {  // WinN: 72 rows, one wave each
    int wid = bid * 4 + (tid >> 6), lane = tid & 63;
    if (wid < 72) {
      const float* v = in_v + (size_t)wid * 512;
      float ss = 0.f;
      for (int c = lane; c < 512; c += 64) ss += v[c] * v[c];
      #pragma unroll
      for (int o = 32; o; o >>= 1) ss += __shfl_xor(ss, o);
      float sc = in_g[wid] / sqrtf(ss);
      float* dst = ws + OFF_WINN + (size_t)wid * 512;
      for (int c = lane; c < 512; c += 64) dst[c] = v[c] * sc;
    }
  } else if (bid < 36) {  // WoutS [c][72]
    int r = (bid - 18) * 256 + tid;
    if (r < 4608) {
      int i = r >> 9, c = r & 511;
      const float* v = out_v + (size_t)r * 8;
      float ss = 0.f;
      #pragma unroll
      for (int d = 0; d < 8; d++) ss += v[d] * v[d];
      float sc = out_g[r] / sqrtf(ss);
      float* dst = ws + OFF_WOUT + (size_t)c * 72 + i * 8;
      #pragma unroll
      for (int d = 0; d < 8; d++) dst[d] = v[d] * sc;
    }
  } else if (bid < 72) {  // codebook scalars
    int r = (bid - 36) * 256 + tid;
    if (r < 9216) {
      int i = r >> 10, j = r & 1023;
      const float* v = codebooks + (size_t)r * 8;
      float ss = 0.f;
      #pragma unroll
      for (int d = 0; d < 8; d++) ss += v[d] * v[d];
      float nm = fmaxf(sqrtf(ss), EPSN);
      float nsq = 0.f;
      #pragma unroll
      for (int d = 0; d < 8; d++) { float cn = v[d] / nm; nsq += cn * cn; }
      ws[OFF_CBS + ((size_t)i * 2 + 0) * 1024 + j] = 2.0f / nm;
      ws[OFF_CBS + ((size_t)i * 2 + 1) * 1024 + j] = nsq;
    }
  } else {  // bias sum
    int c = (bid - 72) * 256 + tid;
    if (c < 512) {
      float s = 0.f;
      #pragma unroll
      for (int j = 0; j < 9; j++) s += out_b[j * 512 + c];
      ws[OFF_BSUM + c] = s;
    }
  }
}

__global__ void prep2(const float* __restrict__ in_b, const float* __restrict__ out_b,
                      float* __restrict__ ws) {
  int gw = blockIdx.x * 4 + (threadIdx.x >> 6), lane = threadIdx.x & 63;
  const float* WinN = ws + OFF_WINN;
  const float* WoutS = ws + OFF_WOUT;
  if (gw < 2304) {  // P tri blocks, row stride 65
    int tri = gw >> 6, dd = gw & 63;
    int ip = 1;
    while (tri >= ip * (ip + 1) / 2) ip++;
    int i = tri - ip * (ip - 1) / 2;
    int d = dd >> 3, dp = dd & 7;
    const float* a = WinN + (size_t)(ip * 8 + d) * 512;
    float s = 0.f;
    for (int c = lane; c < 512; c += 64) s += a[c] * WoutS[(size_t)c * 72 + i * 8 + dp];
    #pragma unroll
    for (int o = 32; o; o >>= 1) s += __shfl_xor(s, o);
    if (lane == 0) ws[OFF_PT + (size_t)tri * 65 + dd] = s;
  } else if (gw < 2376) {  // beff
    int r = gw - 2304;
    int i = r >> 3;
    const float* a = WinN + (size_t)r * 512;
    float s = 0.f;
    for (int c = lane; c < 512; c += 64) {
      float ob = 0.f;
      for (int j = 0; j < i; j++) ob += out_b[j * 512 + c];
      s += a[c] * ob;
    }
    #pragma unroll
    for (int o = 32; o; o >>= 1) s += __shfl_xor(s, o);
    if (lane == 0) ws[OFF_BEFF + r] = in_b[r] - s;
  }
}

// ---------------- tiled MFMA GEMM with in-register splits ----------------
// Tile 128(m) x 128(n), BK=32, 4 waves (2x2), each wave 64x64 (4x4 fragments).
// A: fp32 row-major [M][K], fragments direct from global (L2-hot weights).
// B: fp32 staged in LDS [32][BSTR] (padded), per-mode gather:
//   GM 0: stride-2 conv gather from [b][512][2*TT] (down1: z, down2: x1)
//   GM 2: plain [K][N] rows (up1: zqf)
//   GM 3: up2 gather from u1f [1024][16384]: B[c][n] = u1f[2c+kap(t1)][b*2048+t2]
// EPI 0: Out[(b*512+o)*TT + t] + bias[o]      (down1 -> x1, down2 -> x2)
// EPI 1: Out[m*N + n] + bias[m>>1]            (up1 -> u1f)
// EPI 2: final x[(b*512+o)*8192 + 2*t1 + kap] + bias[o]  (up2 -> d_out)
template <int NS, int GM, int EPI, int TT>
__global__ __launch_bounds__(256) void gemmT(const float* __restrict__ Af,
                                             const float* __restrict__ Bsrc,
                                             const float* __restrict__ bias,
                                             float* __restrict__ Out,
                                             int K, int N) {
  constexpr int BSTR = (GM == 3) ? 132 : 129;
  constexpr int TSH = (TT == 4096) ? 12 : (TT == 2048) ? 11 : 14;
  __shared__ float Bls[32 * BSTR];
  const int tid = threadIdx.x;
  const int w = tid >> 6, l = tid & 63;
  const int g = l >> 4, li = l & 15;
  const int wr = w >> 1, wc = w & 1;
  const int n0 = blockIdx.x * 128, m0 = blockIdx.y * 128;
  const int kl = tid >> 3, sub = tid & 7;

  f32x4 acc[4][4];
  #pragma unroll
  for (int a = 0; a < 4; a++)
    #pragma unroll
    for (int b = 0; b < 4; b++) acc[a][b] = (f32x4){0.f, 0.f, 0.f, 0.f};

  for (int k0 = 0; k0 < K; k0 += 32) {
    __syncthreads();
    // ---- stage B tile (fp32) ----
    if constexpr (GM == 0) {
      int k = k0 + kl;
      int kap = k >> 9, ich = k & 511;
      int b = n0 >> TSH;
      int tb = (n0 & (TT - 1)) + sub * 16;
      const float* p = Bsrc + ((size_t)(b * 512 + ich)) * (2 * TT) + 2 * tb;
      float v[16];
      #pragma unroll
      for (int q4 = 0; q4 < 4; ++q4) {
        float4 lo = *(const float4*)(p + q4 * 8);
        float4 hi = *(const float4*)(p + q4 * 8 + 4);
        if (kap) { v[q4*4+0] = lo.y; v[q4*4+1] = lo.w; v[q4*4+2] = hi.y; v[q4*4+3] = hi.w; }
        else     { v[q4*4+0] = lo.x; v[q4*4+1] = lo.z; v[q4*4+2] = hi.x; v[q4*4+3] = hi.z; }
      }
      #pragma unroll
      for (int i = 0; i < 16; ++i) Bls[kl * BSTR + sub * 16 + i] = v[i];
    } else if constexpr (GM == 2) {
      const float* p = Bsrc + (size_t)(k0 + kl) * N + n0 + sub * 16;
      #pragma unroll
      for (int q4 = 0; q4 < 4; ++q4) {
        float4 f = *(const float4*)(p + q4 * 4);
        Bls[kl * BSTR + sub * 16 + q4*4+0] = f.x;
        Bls[kl * BSTR + sub * 16 + q4*4+1] = f.y;
        Bls[kl * BSTR + sub * 16 + q4*4+2] = f.z;
        Bls[kl * BSTR + sub * 16 + q4*4+3] = f.w;
      }
    } else {  // GM == 3
      int kap = sub >> 2, tq = sub & 3;
      int b = n0 >> 12;
      int t20 = ((n0 & 4095) >> 1) + tq * 16;
      const float* p = Bsrc + (size_t)(2 * (k0 + kl) + kap) * 16384 + b * 2048 + t20;
      #pragma unroll
      for (int q4 = 0; q4 < 4; ++q4) {
        float4 f = *(const float4*)(p + q4 * 4);
        int base = kl * BSTR + kap * 66 + tq * 16 + q4 * 4;
        Bls[base + 0] = f.x; Bls[base + 1] = f.y;
        Bls[base + 2] = f.z; Bls[base + 3] = f.w;
      }
    }
    __syncthreads();

    // ---- B fragments: LDS fp32 -> in-reg split ----
    bf16x8 bfr[4][NS];
    #pragma unroll
    for (int fn = 0; fn < 4; ++fn) {
      int tl = wc * 64 + fn * 16 + li;
      int base;
      if constexpr (GM == 3) base = (tl & 1) * 66 + (tl >> 1);
      else base = tl;
      float bv[8];
      #pragma unroll
      for (int j = 0; j < 8; ++j) bv[j] = Bls[(g * 8 + j) * BSTR + base];
      tsplit<NS>(bv, bfr[fn]);
    }

    // ---- A fragments direct from global + MFMA ----
    const float* arow = Af + (size_t)(m0 + wr * 64 + li) * K + k0 + g * 8;
    #pragma unroll
    for (int fm = 0; fm < 4; ++fm) {
      float av[8];
      *(float4*)&av[0] = *(const float4*)(arow + (size_t)fm * 16 * K);
      *(float4*)&av[4] = *(const float4*)(arow + (size_t)fm * 16 * K + 4);
      bf16x8 afr[NS];
      tsplit<NS>(av, afr);
      #pragma unroll
      for (int fn = 0; fn < 4; ++fn)
        acc[fm][fn] = mmaN<NS>(afr, bfr[fn], acc[fm][fn]);
    }
  }

  // ---- epilogue ----
  const int mb = m0 + wr * 64 + g * 4;
  const int nb = n0 + wc * 64 + li;
  if constexpr (EPI == 0) {
    #pragma unroll
    for (int fn = 0; fn < 4; ++fn) {
      int n = nb + fn * 16;
      int b = n >> TSH, t = n & (TT - 1);
      #pragma unroll
      for (int fm = 0; fm < 4; ++fm)
        #pragma unroll
        for (int r = 0; r < 4; ++r) {
          int o = mb + fm * 16 + r;
          Out[((size_t)((b << 9) + o)) * TT + t] = acc[fm][fn][r] + bias[o];
        }
    }
  } else if constexpr (EPI == 1) {
    #pragma unroll
    for (int fn = 0; fn < 4; ++fn) {
      int n = nb + fn * 16;
      #pragma unroll
      for (int fm = 0; fm < 4; ++fm)
        #pragma unroll
        for (int r = 0; r < 4; ++r) {
          int m = mb + fm * 16 + r;
          Out[(size_t)m * N + n] = acc[fm][fn][r] + bias[m >> 1];
        }
    }
  } else {  // EPI == 2: final x
    #pragma unroll
    for (int fn = 0; fn < 4; ++fn) {
      int n = nb + fn * 16;
      int b = n >> 12, t1 = n & 4095;
      #pragma unroll
      for (int fm = 0; fm < 4; ++fm)
        #pragma unroll
        for (int rp = 0; rp < 2; ++rp) {
          int m2 = mb + fm * 16 + 2 * rp;
          int o = m2 >> 1;
          float bv = bias[o];
          float2 st = make_float2(acc[fm][fn][2 * rp] + bv, acc[fm][fn][2 * rp + 1] + bv);
          *(float2*)&Out[((size_t)((b << 9) + o)) * 8192 + 2 * t1] = st;
        }
    }
  }
}

// ---------------- proven fp32 tiled GEMM (e0, zq) ----------------
// GATHER: 1=BT (per-b [k][Tt]), 2=FLAT ([k][N], guard k<K)
// SCATTER: 0=NORM ([b][m][Tt] + bias), 1=E0T ([n][M])
template <int GATHER, int SCATTER>
__global__ __launch_bounds__(256) void gemm_conv(const float* __restrict__ A,
                                                 const float* __restrict__ Bsrc,
                                                 const float* __restrict__ bias,
                                                 float* __restrict__ Out,
                                                 int M, int K, int N, int Tt) {
  constexpr int BM = 128, BN = 128, BK = 16;
  __shared__ float As[BK][BM + 4];
  __shared__ float Bs[BK][BN + 4];
  int tid = threadIdx.x;
  int tx = tid & 15, ty = tid >> 4;
  int n0 = blockIdx.x * BN, m0 = blockIdx.y * BM;
  int b = n0 / Tt, t0 = n0 % Tt;
  float acc[8][8];
  #pragma unroll
  for (int i = 0; i < 8; i++)
    #pragma unroll
    for (int j = 0; j < 8; j++) acc[i][j] = 0.f;

  for (int k0 = 0; k0 < K; k0 += BK) {
    #pragma unroll
    for (int rep = 0; rep < 2; rep++) {
      int f = tid + rep * 256;
      int row = f >> 2, c4 = (f & 3) << 2;
      int m = m0 + row, k = k0 + c4;
      float4 v = make_float4(0.f, 0.f, 0.f, 0.f);
      if (m < M) {
        if (k + 3 < K) {
          v = *(const float4*)(A + (size_t)m * K + k);
        } else {
          float tmp[4] = {0.f, 0.f, 0.f, 0.f};
          for (int c = 0; c < 4; c++)
            if (k + c < K) tmp[c] = A[(size_t)m * K + k + c];
          v = make_float4(tmp[0], tmp[1], tmp[2], tmp[3]);
        }
      }
      As[c4 + 0][row] = v.x; As[c4 + 1][row] = v.y;
      As[c4 + 2][row] = v.z; As[c4 + 3][row] = v.w;
    }
    #pragma unroll
    for (int rep = 0; rep < 2; rep++) {
      int f = tid + rep * 256;
      int kk = f >> 5, n4 = (f & 31) << 2;
      int k = k0 + kk;
      float4 v = make_float4(0.f, 0.f, 0.f, 0.f);
      if (GATHER == 1) {
        v = *(const float4*)(Bsrc + ((size_t)(b * K + k)) * Tt + t0 + n4);
      } else {
        if (k < K) v = *(const float4*)(Bsrc + (size_t)k * N + n0 + n4);
      }
      *(float4*)&Bs[kk][n4] = v;
    }
    __syncthreads();
    #pragma unroll
    for (int kk = 0; kk < BK; kk++) {
      float a[8], bb[8];
      *(float4*)&a[0] = *(float4*)&As[kk][ty * 8];
      *(float4*)&a[4] = *(float4*)&As[kk][ty * 8 + 4];
      *(float4*)&bb[0] = *(float4*)&Bs[kk][tx * 8];
      *(float4*)&bb[4] = *(float4*)&Bs[kk][tx * 8 + 4];
      #pragma unroll
      for (int i = 0; i < 8; i++)
        #pragma unroll
        for (int j = 0; j < 8; j++) acc[i][j] = fmaf(a[i], bb[j], acc[i][j]);
    }
    __syncthreads();
  }
  if (SCATTER == 0) {
    #pragma unroll
    for (int i = 0; i < 8; i++) {
      int m = m0 + ty * 8 + i;
      if (m < M) {
        float bv = bias ? bias[m] : 0.f;
        float* p = Out + ((size_t)(b * M + m)) * Tt + t0 + tx * 8;
        *(float4*)p = make_float4(acc[i][0] + bv, acc[i][1] + bv, acc[i][2] + bv, acc[i][3] + bv);
        *(float4*)(p + 4) = make_float4(acc[i][4] + bv, acc[i][5] + bv, acc[i][6] + bv, acc[i][7] + bv);
      }
    }
  } else {
    #pragma unroll
    for (int j = 0; j < 8; j++) {
      int n = n0 + tx * 8 + j;
      int m = m0 + ty * 8;
      if (m < M) {
        float* p = Out + (size_t)n * M + m;
        if (m + 7 < M) {
          *(float4*)p = make_float4(acc[0][j], acc[1][j], acc[2][j], acc[3][j]);
          *(float4*)(p + 4) = make_float4(acc[4][j], acc[5][j], acc[6][j], acc[7][j]);
        } else {
          for (int i = 0; i < 8 && m + i < M; i++) p[i] = acc[i][j];
        }
      }
    }
  }
}

// ---------------- RVQ core (proven) ----------------
__global__ __launch_bounds__(256) void rvq_kernel(const float* __restrict__ codebooks,
                                                  const float* __restrict__ e0t,
                                                  const float* __restrict__ cbsW,
                                                  const float* __restrict__ ptW,
                                                  const float* __restrict__ beffW,
                                                  float* __restrict__ Qout,
                                                  float* __restrict__ codesOut,
                                                  float* __restrict__ lossPart) {
  __shared__ float cbv[8][1024];
  __shared__ float cbs2[2][1024];
  __shared__ float Pt[36 * 65];
  __shared__ float est[16][72];
  __shared__ float lred[4];
  int tid = threadIdx.x, wid = tid >> 6, lane = tid & 63;
  int nb0 = blockIdx.x * 16;
  for (int idx = tid; idx < 2340; idx += 256) Pt[idx] = ptW[idx];
  for (int idx = tid; idx < 16 * 72; idx += 256)
    est[idx / 72][idx % 72] = e0t[(size_t)nb0 * 72 + idx] + beffW[idx % 72];
  float lossLocal = 0.f;

  for (int i = 0; i < NQ; i++) {
    __syncthreads();
    const float* cbg = codebooks + (size_t)i * CBS * CBD;
    for (int lin = tid; lin < 2048; lin += 256) {
      int j = lin >> 1, half = (lin & 1) << 2;
      float4 v = *(const float4*)(cbg + (size_t)j * 8 + half);
      cbv[half + 0][j] = v.x; cbv[half + 1][j] = v.y;
      cbv[half + 2][j] = v.z; cbv[half + 3][j] = v.w;
    }
    for (int lin = tid; lin < 1024; lin += 256) {
      cbs2[0][lin] = cbsW[((size_t)i * 2 + 0) * 1024 + lin];
      cbs2[1][lin] = cbsW[((size_t)i * 2 + 1) * 1024 + lin];
    }
    __syncthreads();

    float ze[4][8], en[4][8];
    #pragma unroll
    for (int w = 0; w < 4; w++) {
      int tokl = wid * 4 + w;
      float ss = 0.f;
      #pragma unroll
      for (int d = 0; d < 8; d++) { float v = est[tokl][i * 8 + d]; ze[w][d] = v; ss += v * v; }
      float inv = 1.0f / fmaxf(sqrtf(ss), EPSN);
      #pragma unroll
      for (int d = 0; d < 8; d++) en[w][d] = ze[w][d] * inv;
    }
    float best[4]; int bidx[4];
    #pragma unroll
    for (int w = 0; w < 4; w++) { best[w] = -INFINITY; bidx[w] = 0; }
    #pragma unroll 4
    for (int r = 0; r < 16; r++) {
      int j = lane + (r << 6);
      float c0 = cbv[0][j], c1 = cbv[1][j], c2 = cbv[2][j], c3 = cbv[3][j];
      float c4 = cbv[4][j], c5 = cbv[5][j], c6 = cbv[6][j], c7 = cbv[7][j];
      float ti = cbs2[0][j], ns = cbs2[1][j];
      #pragma unroll
      for (int w = 0; w < 4; w++) {
        float dt = en[w][0] * c0;
        dt = fmaf(en[w][1], c1, dt); dt = fmaf(en[w][2], c2, dt);
        dt = fmaf(en[w][3], c3, dt); dt = fmaf(en[w][4], c4, dt);
        dt = fmaf(en[w][5], c5, dt); dt = fmaf(en[w][6], c6, dt);
        dt = fmaf(en[w][7], c7, dt);
        float s = fmaf(dt, ti, -ns);
        if (s > best[w]) { best[w] = s; bidx[w] = j; }
      }
    }
    #pragma unroll
    for (int w = 0; w < 4; w++) {
      #pragma unroll
      for (int off = 32; off; off >>= 1) {
        float so = __shfl_xor(best[w], off);
        int jo = __shfl_xor(bidx[w], off);
        if (so > best[w] || (so == best[w] && jo < bidx[w])) { best[w] = so; bidx[w] = jo; }
      }
    }
    int d = lane & 7;
    #pragma unroll
    for (int w = 0; w < 4; w++) {
      int jstar = bidx[w];
      int tokl = wid * 4 + w;
      int n = nb0 + tokl;
      float qd = cbv[d][jstar];
      float diff = ze[w][d] - qd;
      float sq = diff * diff;
      sq += __shfl_xor(sq, 1); sq += __shfl_xor(sq, 2); sq += __shfl_xor(sq, 4);
      if (lane == 0) lossLocal += sq;
      if (lane < 8) Qout[(size_t)(i * 8 + lane) * NTOK + n] = qd;
      if (lane == 0) codesOut[(size_t)((n >> 11) * NQ + i) * TQ + (n & (TQ - 1))] = (float)jstar;
      if (i < NQ - 1) {
        int f = lane >> 3, d2 = lane & 7;
        int ip = i + 1 + f;
        if (ip < NQ) {
          int tri = (ip * (ip - 1)) / 2 + i;
          const float* prow = &Pt[tri * 65 + d2 * 8];
          float s = 0.f;
          #pragma unroll
          for (int dp = 0; dp < 8; dp++) s = fmaf(prow[dp], cbv[dp][jstar], s);
          est[tokl][ip * 8 + d2] -= s;
        }
      }
    }
  }
  if (lane == 0) lred[wid] = lossLocal;
  __syncthreads();
  if (tid == 0) {
    float s = ((lred[0] + lred[1]) + lred[2]) + lred[3];
    lossPart[blockIdx.x] = s;
  }
}

__global__ void loss_fin(const float* __restrict__ lossPart, float* __restrict__ out) {
  __shared__ float s[256];
  int tid = threadIdx.x;
  float v = 0.f;
  for (int r = 0; r < 4; r++) v += lossPart[tid + r * 256];
  s[tid] = v;
  __syncthreads();
  for (int w = 128; w; w >>= 1) {
    if (tid < w) s[tid] += s[tid + w];
    __syncthreads();
  }
  if (tid == 0) {
    float total = s[0] / 131072.0f;
    out[0] = total;
    out[1] = total;
  }
}

// ---------------- launch ----------------
extern "C" void kernel_launch(void* const* d_in, const int* in_sizes, int n_in,
                              void* d_out, int out_size, void* d_ws, size_t ws_size,
                              hipStream_t stream) {
  const float* z      = (const float*)d_in[0];
  const float* down_w = (const float*)d_in[1];
  const float* down_b = (const float*)d_in[2];
  const float* up_w   = (const float*)d_in[3];
  const float* up_b   = (const float*)d_in[4];
  const float* in_v   = (const float*)d_in[5];
  const float* in_g   = (const float*)d_in[6];
  const float* in_b   = (const float*)d_in[7];
  const float* out_v  = (const float*)d_in[8];
  const float* out_g  = (const float*)d_in[9];
  const float* out_b  = (const float*)d_in[10];
  const float* codebooks = (const float*)d_in[11];
  float* ws = (float*)d_ws;
  float* xout = (float*)d_out;
  float* codesOut = xout + (size_t)8 * 512 * 8192;
  float* lossOut = codesOut + (size_t)8 * NQ * TQ;

  hipLaunchKernelGGL(prep_wf, dim3(8192), dim3(256), 0, stream, down_w, up_w, ws);
  hipLaunchKernelGGL(prep_small1, dim3(74), dim3(256), 0, stream,
                     in_v, in_g, out_v, out_g, out_b, codebooks, ws);
  hipLaunchKernelGGL(prep2, dim3(594), dim3(256), 0, stream, in_b, out_b, ws);
  // down1 (MFMA 3-split): A=dwf0 [512][1024], B=z gather -> x1 [8][512][4096]
  hipLaunchKernelGGL((gemmT<3, 0, 0, 4096>), dim3(256, 4), dim3(256), 0, stream,
                     ws + OFF_DWF, z, down_b, ws + OFF_X1, 1024, 32768);
  // down2 (MFMA 3-split): A=dwf1, B=x1 gather -> x2 [8][512][2048]
  hipLaunchKernelGGL((gemmT<3, 0, 0, 2048>), dim3(128, 4), dim3(256), 0, stream,
                     ws + OFF_DWF + 524288, ws + OFF_X1, down_b + 512, ws + OFF_X2, 1024, 16384);
  // e0 (fp32) = WinN[72,512] @ x2 -> e0t [16384][72]
  hipLaunchKernelGGL((gemm_conv<1, 1>), dim3(128, 1), dim3(256), 0, stream,
                     ws + OFF_WINN, ws + OFF_X2, (const float*)nullptr, ws + OFF_E0T, 72, 512, 16384, 2048);
  // RVQ
  hipLaunchKernelGGL(rvq_kernel, dim3(1024), dim3(256), 0, stream,
                     codebooks, ws + OFF_E0T, ws + OFF_CBS, ws + OFF_PT, ws + OFF_BEFF,
                     ws + OFF_Q, codesOut, ws + OFF_LOSS);
  // zq (fp32, K=72): WoutS[512][72] @ Q[72][16384] + bsum -> zqf [512][16384]
  hipLaunchKernelGGL((gemm_conv<2, 0>), dim3(128, 4), dim3(256), 0, stream,
                     ws + OFF_WOUT, ws + OFF_Q, ws + OFF_BSUM, ws + OFF_ZQF, 512, 72, 16384, 16384);
  // up1 (MFMA 2-split): A=uwf0 [1024][512], B=zqf rows -> u1f [1024][16384]
  hipLaunchKernelGGL((gemmT<2, 2, 1, 4096>), dim3(128, 8), dim3(256), 0, stream,
                     ws + OFF_UWF, ws + OFF_ZQF, up_b, ws + OFF_U1F, 512, 16384);
  // up2 (MFMA 2-split): A=uwf1 [1024][512], B=u1f gather -> x fp32 to d_out
  hipLaunchKernelGGL((gemmT<2, 3, 2, 4096>), dim3(256, 8), dim3(256), 0, stream,
                     ws + OFF_UWF + 524288, ws + OFF_U1F, up_b + 512, xout, 512, 32768);
  hipLaunchKernelGGL(loss_fin, dim3(1), dim3(256), 0, stream, ws + OFF_LOSS, lossOut);
}

// Round 9
// 1048.571 us; speedup vs baseline: 1.5259x; 1.2553x over previous
//
#include <hip/hip_runtime.h>
#include <math.h>

// FireflyVQ R9: gemmT v2 - split-once-at-staging into n-major bf16 LDS planes,
// pre-split A weight planes, register prefetch of next B tile.
// down1/down2 NS=3 (code-safe), up1/up2 NS=2. e0/zq fp32 gemm_conv; RVQ unchanged.

using u16 = unsigned short;
typedef __attribute__((ext_vector_type(8))) short bf16x8;
typedef __attribute__((ext_vector_type(4))) u16 su16x4;
typedef __attribute__((ext_vector_type(4))) float f32x4;

constexpr int NQ = 9, CBS = 1024, CBD = 8;
constexpr int TQ = 2048;
constexpr int NTOK = 16384;
constexpr int ASTR = 524288;   // u16 elems per weight plane
#define EPSN 1e-12f

// ---- ws layout (float offsets). Region A = [0, 16777216): Z2 (down1->down2),
// then Q/e0t sub-slots (rvq), then U2 (up1->up2). x2 region reused for zqf.
constexpr size_t OFF_Z2   = 0;                         // Z2 [1024][16384]
constexpr size_t OFF_U2   = 0;                         // U2 [512][32768] (alias)
constexpr size_t OFF_Q    = 14417920;                  // Q [72][16384] (region A sub)
constexpr size_t OFF_E0T  = 15597568;                  // e0t [16384][72] (region A sub)
constexpr size_t OFF_X2   = 16777216;                  // x2 [8][512][2048]
constexpr size_t OFF_ZQF  = OFF_X2;                    // zqf [512][16384] (alias)
constexpr size_t OFF_DWP  = OFF_X2 + 8388608;          // 1,572,864 fl (2l x 3p x 512K u16)
constexpr size_t OFF_UWP  = OFF_DWP + 1572864;         // 1,048,576 fl (2l x 2p x 512K u16)
constexpr size_t OFF_WINN = OFF_UWP + 1048576;         // 36,864
constexpr size_t OFF_WOUT = OFF_WINN + 36864;          // 36,864
constexpr size_t OFF_CBS  = OFF_WOUT + 36864;          // 18,432
constexpr size_t OFF_PT   = OFF_CBS + 18432;           // 2,340
constexpr size_t OFF_BEFF = OFF_PT + 2340;             // 72
constexpr size_t OFF_BSUM = OFF_BEFF + 72;             // 512
constexpr size_t OFF_LOSS = OFF_BSUM + 512;            // 1,024  (end ~111.5 MB)

// ---------------- prep: weight planes (truncation split) ----------------
__global__ void prep_wp(const float* __restrict__ down_w, const float* __restrict__ up_w,
                        float* __restrict__ ws) {
  int idx = blockIdx.x * 256 + threadIdx.x;   // [0, 4*524288)
  int mat = idx >> 19, e = idx & 524287;
  if (mat < 2) {  // dwp[l][p][o][k=kap*512+i]
    int o = e >> 10, k = e & 1023, kap = k >> 9, i = k & 511;
    float v = down_w[((size_t)(mat * 512 + o) * 512 + i) * 2 + kap];
    u16* dst = (u16*)(ws + OFF_DWP) + (size_t)mat * 3 * ASTR;
    unsigned u = __float_as_uint(v);
    dst[e] = (u16)(u >> 16);
    float r = v - __uint_as_float(u & 0xFFFF0000u);
    unsigned ur = __float_as_uint(r);
    dst[ASTR + e] = (u16)(ur >> 16);
    float r2 = r - __uint_as_float(ur & 0xFFFF0000u);
    dst[2 * ASTR + e] = (u16)(__float_as_uint(r2) >> 16);
  } else {        // uwp[l][p][m=2o+kap][c]
    int l = mat - 2;
    int m = e >> 9, c = e & 511;
    float v = up_w[(size_t)l * 524288 + ((size_t)c * 512 + (m >> 1)) * 2 + (m & 1)];
    u16* dst = (u16*)(ws + OFF_UWP) + (size_t)l * 2 * ASTR;
    unsigned u = __float_as_uint(v);
    dst[e] = (u16)(u >> 16);
    float r = v - __uint_as_float(u & 0xFFFF0000u);
    dst[ASTR + e] = (u16)(__float_as_uint(r) >> 16);
  }
}

__global__ void prep_small1(const float* __restrict__ in_v, const float* __restrict__ in_g,
                            const float* __restrict__ out_v, const float* __restrict__ out_g,
                            const float* __restrict__ out_b, const float* __restrict__ codebooks,
                            float* __restrict__ ws) {
  int bid = blockIdx.x, tid = threadIdx.x;
  if (bid < 18) {
    int wid = bid * 4 + (tid >> 6), lane = tid & 63;
    if (wid < 72) {
      const float* v = in_v + (size_t)wid * 512;
      float ss = 0.f;
      for (int c = lane; c < 512; c += 64) ss += v[c] * v[c];
      #pragma unroll
      for (int o = 32; o; o >>= 1) ss += __shfl_xor(ss, o);
      float sc = in_g[wid] / sqrtf(ss);
      float* dst = ws + OFF_WINN + (size_t)wid * 512;
      for (int c = lane; c < 512; c += 64) dst[c] = v[c] * sc;
    }
  } else if (bid < 36) {
    int r = (bid - 18) * 256 + tid;
    if (r < 4608) {
      int i = r >> 9, c = r & 511;
      const float* v = out_v + (size_t)r * 8;
      float ss = 0.f;
      #pragma unroll
      for (int d = 0; d < 8; d++) ss += v[d] * v[d];
      float sc = out_g[r] / sqrtf(ss);
      float* dst = ws + OFF_WOUT + (size_t)c * 72 + i * 8;
      #pragma unroll
      for (int d = 0; d < 8; d++) dst[d] = v[d] * sc;
    }
  } else if (bid < 72) {
    int r = (bid - 36) * 256 + tid;
    if (r < 9216) {
      int i = r >> 10, j = r & 1023;
      const float* v = codebooks + (size_t)r * 8;
      float ss = 0.f;
      #pragma unroll
      for (int d = 0; d < 8; d++) ss += v[d] * v[d];
      float nm = fmaxf(sqrtf(ss), EPSN);
      float nsq = 0.f;
      #pragma unroll
      for (int d = 0; d < 8; d++) { float cn = v[d] / nm; nsq += cn * cn; }
      ws[OFF_CBS + ((size_t)i * 2 + 0) * 1024 + j] = 2.0f / nm;
      ws[OFF_CBS + ((size_t)i * 2 + 1) * 1024 + j] = nsq;
    }
  } else {
    int c = (bid - 72) * 256 + tid;
    if (c < 512) {
      float s = 0.f;
      #pragma unroll
      for (int j = 0; j < 9; j++) s += out_b[j * 512 + c];
      ws[OFF_BSUM + c] = s;
    }
  }
}

__global__ void prep2(const float* __restrict__ in_b, const float* __restrict__ out_b,
                      float* __restrict__ ws) {
  int gw = blockIdx.x * 4 + (threadIdx.x >> 6), lane = threadIdx.x & 63;
  const float* WinN = ws + OFF_WINN;
  const float* WoutS = ws + OFF_WOUT;
  if (gw < 2304) {
    int tri = gw >> 6, dd = gw & 63;
    int ip = 1;
    while (tri >= ip * (ip + 1) / 2) ip++;
    int i = tri - ip * (ip - 1) / 2;
    int d = dd >> 3, dp = dd & 7;
    const float* a = WinN + (size_t)(ip * 8 + d) * 512;
    float s = 0.f;
    for (int c = lane; c < 512; c += 64) s += a[c] * WoutS[(size_t)c * 72 + i * 8 + dp];
    #pragma unroll
    for (int o = 32; o; o >>= 1) s += __shfl_xor(s, o);
    if (lane == 0) ws[OFF_PT + (size_t)tri * 65 + dd] = s;
  } else if (gw < 2376) {
    int r = gw - 2304;
    int i = r >> 3;
    const float* a = WinN + (size_t)r * 512;
    float s = 0.f;
    for (int c = lane; c < 512; c += 64) {
      float ob = 0.f;
      for (int j = 0; j < i; j++) ob += out_b[j * 512 + c];
      s += a[c] * ob;
    }
    #pragma unroll
    for (int o = 32; o; o >>= 1) s += __shfl_xor(s, o);
    if (lane == 0) ws[OFF_BEFF + r] = in_b[r] - s;
  }
}

// ---------------- gemmT v2 ----------------
// Tile 128m x 128n, BK=32, 4 waves (2x2). A: pre-split u16 planes [M][K].
// B: fp32 global -> reg prefetch -> truncation split at staging -> NS bf16
// LDS planes n-major [128][40] (pad 40 -> conflict-uniform b128 frag reads).
// GM 0: down1 z-gather [b][512][8192]; GM 2: plain rows [K][N].
// EPI 0: down1 -> Z2[(t1&1)*512+o][b*2048+t1>>1] + bias[o]    (b=n>>12)
// EPI 1: down2 -> x2[((b<<9)+o)*2048+t] + bias[o]             (b=n>>11)
// EPI 2: up1   -> U2[o][b*4096+2t+kap] + bias[o] float2        (b=n>>11)
// EPI 3: up2   -> x[((b<<9)+o)*8192+2*t1+kap] + bias[o] float2 (b=n>>12)
template <int NS, int GM, int EPI>
__global__ __launch_bounds__(256) void gemmT(const u16* __restrict__ Ap,
                                             const float* __restrict__ Bsrc,
                                             const float* __restrict__ bias,
                                             float* __restrict__ Out,
                                             int K, int N) {
  __shared__ u16 Bp[NS][128 * 40];
  const int tid = threadIdx.x;
  const int w = tid >> 6, l = tid & 63;
  const int g = l >> 4, li = l & 15;
  const int wr = w >> 1, wc = w & 1;
  const int n0 = blockIdx.x * 128, m0 = blockIdx.y * 128;
  const int kq = tid >> 5, nq = tid & 31;

  f32x4 acc[4][4];
  #pragma unroll
  for (int a = 0; a < 4; a++)
    #pragma unroll
    for (int b = 0; b < 4; b++) acc[a][b] = (f32x4){0.f, 0.f, 0.f, 0.f};

  float4 pr[8];

#define LOADB(K0)                                                                  \
  if constexpr (GM == 0) {                                                         \
    int bb_ = n0 >> 12;                                                            \
    int t0_ = (n0 & 4095) + nq * 4;                                                \
    _Pragma("unroll")                                                              \
    for (int r_ = 0; r_ < 4; ++r_) {                                               \
      int ich_ = ((K0) + kq * 4 + r_) & 511;                                       \
      const float* p_ = Bsrc + ((size_t)(bb_ * 512 + ich_) << 13) + 2 * t0_;       \
      pr[2 * r_] = *(const float4*)p_;                                             \
      pr[2 * r_ + 1] = *(const float4*)(p_ + 4);                                   \
    }                                                                              \
  } else {                                                                         \
    _Pragma("unroll")                                                              \
    for (int r_ = 0; r_ < 4; ++r_)                                                 \
      pr[r_] = *(const float4*)(Bsrc + (size_t)((K0) + kq * 4 + r_) * N + n0 + nq * 4); \
  }

  LOADB(0)

  for (int k0 = 0; k0 < K; k0 += 32) {
    __syncthreads();
    // ---- stage: split pr -> LDS planes
    {
      const int kap = (GM == 0) ? ((k0 + kq * 4) >> 9) : 0;
      #pragma unroll
      for (int j = 0; j < 4; ++j) {
        su16x4 q0, q1, q2;
        #pragma unroll
        for (int r = 0; r < 4; ++r) {
          float v;
          if constexpr (GM == 0) {
            float4 lo = pr[2 * r], hi = pr[2 * r + 1];
            float e0 = kap ? lo.y : lo.x, e1 = kap ? lo.w : lo.z;
            float e2 = kap ? hi.y : hi.x, e3 = kap ? hi.w : hi.z;
            v = (j == 0) ? e0 : (j == 1) ? e1 : (j == 2) ? e2 : e3;
          } else {
            float4 f = pr[r];
            v = (j == 0) ? f.x : (j == 1) ? f.y : (j == 2) ? f.z : f.w;
          }
          unsigned u = __float_as_uint(v);
          q0[r] = (u16)(u >> 16);
          float rr = v - __uint_as_float(u & 0xFFFF0000u);
          unsigned ur = __float_as_uint(rr);
          q1[r] = (u16)(ur >> 16);
          if constexpr (NS == 3) {
            float r2 = rr - __uint_as_float(ur & 0xFFFF0000u);
            q2[r] = (u16)(__float_as_uint(r2) >> 16);
          }
        }
        int off = (nq * 4 + j) * 40 + kq * 4;
        *(su16x4*)&Bp[0][off] = q0;
        *(su16x4*)&Bp[1][off] = q1;
        if constexpr (NS == 3) *(su16x4*)&Bp[2][off] = q2;
      }
    }
    __syncthreads();
    if (k0 + 32 < K) { LOADB(k0 + 32) }

    // ---- fragments + MFMA
    bf16x8 bfr[4][NS];
    #pragma unroll
    for (int fn = 0; fn < 4; ++fn) {
      int row = wc * 64 + fn * 16 + li;
      #pragma unroll
      for (int q = 0; q < NS; ++q)
        bfr[fn][q] = *(const bf16x8*)&Bp[q][row * 40 + g * 8];
    }
    const u16* arow = Ap + (size_t)(m0 + wr * 64 + li) * K + k0 + g * 8;
    #pragma unroll
    for (int fm = 0; fm < 4; ++fm) {
      bf16x8 afr[NS];
      #pragma unroll
      for (int p = 0; p < NS; ++p)
        afr[p] = *(const bf16x8*)(arow + (size_t)p * ASTR + (size_t)fm * 16 * K);
      #pragma unroll
      for (int fn = 0; fn < 4; ++fn) {
        f32x4 a = acc[fm][fn];
        if constexpr (NS == 3) {
          a = __builtin_amdgcn_mfma_f32_16x16x32_bf16(afr[2], bfr[fn][0], a, 0, 0, 0);
          a = __builtin_amdgcn_mfma_f32_16x16x32_bf16(afr[1], bfr[fn][1], a, 0, 0, 0);
          a = __builtin_amdgcn_mfma_f32_16x16x32_bf16(afr[0], bfr[fn][2], a, 0, 0, 0);
          a = __builtin_amdgcn_mfma_f32_16x16x32_bf16(afr[1], bfr[fn][0], a, 0, 0, 0);
          a = __builtin_amdgcn_mfma_f32_16x16x32_bf16(afr[0], bfr[fn][1], a, 0, 0, 0);
          a = __builtin_amdgcn_mfma_f32_16x16x32_bf16(afr[0], bfr[fn][0], a, 0, 0, 0);
        } else {
          a = __builtin_amdgcn_mfma_f32_16x16x32_bf16(afr[1], bfr[fn][0], a, 0, 0, 0);
          a = __builtin_amdgcn_mfma_f32_16x16x32_bf16(afr[0], bfr[fn][1], a, 0, 0, 0);
          a = __builtin_amdgcn_mfma_f32_16x16x32_bf16(afr[0], bfr[fn][0], a, 0, 0, 0);
        }
        acc[fm][fn] = a;
      }
    }
  }
#undef LOADB

  // ---- epilogue
  const int mb = m0 + wr * 64 + g * 4;
  const int nb = n0 + wc * 64 + li;
  if constexpr (EPI == 0) {
    #pragma unroll
    for (int fn = 0; fn < 4; ++fn) {
      int n = nb + fn * 16;
      int b = n >> 12, t1 = n & 4095;
      size_t col = (size_t)b * 2048 + (t1 >> 1);
      int rowbase = (t1 & 1) * 512;
      #pragma unroll
      for (int fm = 0; fm < 4; ++fm)
        #pragma unroll
        for (int r = 0; r < 4; ++r) {
          int o = mb + fm * 16 + r;
          Out[(size_t)(rowbase + o) * 16384 + col] = acc[fm][fn][r] + bias[o];
        }
    }
  } else if constexpr (EPI == 1) {
    #pragma unroll
    for (int fn = 0; fn < 4; ++fn) {
      int n = nb + fn * 16;
      int b = n >> 11, t = n & 2047;
      #pragma unroll
      for (int fm = 0; fm < 4; ++fm)
        #pragma unroll
        for (int r = 0; r < 4; ++r) {
          int o = mb + fm * 16 + r;
          Out[((size_t)((b << 9) + o)) * 2048 + t] = acc[fm][fn][r] + bias[o];
        }
    }
  } else if constexpr (EPI == 2) {
    #pragma unroll
    for (int fn = 0; fn < 4; ++fn) {
      int n = nb + fn * 16;
      int b = n >> 11, t = n & 2047;
      #pragma unroll
      for (int fm = 0; fm < 4; ++fm)
        #pragma unroll
        for (int rp = 0; rp < 2; ++rp) {
          int m2 = mb + fm * 16 + 2 * rp;
          int o = m2 >> 1;
          float bv = bias[o];
          float2 st = make_float2(acc[fm][fn][2 * rp] + bv, acc[fm][fn][2 * rp + 1] + bv);
          *(float2*)&Out[(size_t)o * 32768 + (size_t)b * 4096 + 2 * t] = st;
        }
    }
  } else {  // EPI == 3
    #pragma unroll
    for (int fn = 0; fn < 4; ++fn) {
      int n = nb + fn * 16;
      int b = n >> 12, t1 = n & 4095;
      #pragma unroll
      for (int fm = 0; fm < 4; ++fm)
        #pragma unroll
        for (int rp = 0; rp < 2; ++rp) {
          int m2 = mb + fm * 16 + 2 * rp;
          int o = m2 >> 1;
          float bv = bias[o];
          float2 st = make_float2(acc[fm][fn][2 * rp] + bv, acc[fm][fn][2 * rp + 1] + bv);
          *(float2*)&Out[((size_t)((b << 9) + o)) * 8192 + 2 * t1] = st;
        }
    }
  }
}

// ---------------- proven fp32 tiled GEMM (e0, zq) ----------------
template <int GATHER, int SCATTER>
__global__ __launch_bounds__(256) void gemm_conv(const float* __restrict__ A,
                                                 const float* __restrict__ Bsrc,
                                                 const float* __restrict__ bias,
                                                 float* __restrict__ Out,
                                                 int M, int K, int N, int Tt) {
  constexpr int BM = 128, BN = 128, BK = 16;
  __shared__ float As[BK][BM + 4];
  __shared__ float Bs[BK][BN + 4];
  int tid = threadIdx.x;
  int tx = tid & 15, ty = tid >> 4;
  int n0 = blockIdx.x * BN, m0 = blockIdx.y * BM;
  int b = n0 / Tt, t0 = n0 % Tt;
  float acc[8][8];
  #pragma unroll
  for (int i = 0; i < 8; i++)
    #pragma unroll
    for (int j = 0; j < 8; j++) acc[i][j] = 0.f;

  for (int k0 = 0; k0 < K; k0 += BK) {
    #pragma unroll
    for (int rep = 0; rep < 2; rep++) {
      int f = tid + rep * 256;
      int row = f >> 2, c4 = (f & 3) << 2;
      int m = m0 + row, k = k0 + c4;
      float4 v = make_float4(0.f, 0.f, 0.f, 0.f);
      if (m < M) {
        if (k + 3 < K) {
          v = *(const float4*)(A + (size_t)m * K + k);
        } else {
          float tmp[4] = {0.f, 0.f, 0.f, 0.f};
          for (int c = 0; c < 4; c++)
            if (k + c < K) tmp[c] = A[(size_t)m * K + k + c];
          v = make_float4(tmp[0], tmp[1], tmp[2], tmp[3]);
        }
      }
      As[c4 + 0][row] = v.x; As[c4 + 1][row] = v.y;
      As[c4 + 2][row] = v.z; As[c4 + 3][row] = v.w;
    }
    #pragma unroll
    for (int rep = 0; rep < 2; rep++) {
      int f = tid + rep * 256;
      int kk = f >> 5, n4 = (f & 31) << 2;
      int k = k0 + kk;
      float4 v = make_float4(0.f, 0.f, 0.f, 0.f);
      if (GATHER == 1) {
        v = *(const float4*)(Bsrc + ((size_t)(b * K + k)) * Tt + t0 + n4);
      } else {
        if (k < K) v = *(const float4*)(Bsrc + (size_t)k * N + n0 + n4);
      }
      *(float4*)&Bs[kk][n4] = v;
    }
    __syncthreads();
    #pragma unroll
    for (int kk = 0; kk < BK; kk++) {
      float a[8], bb[8];
      *(float4*)&a[0] = *(float4*)&As[kk][ty * 8];
      *(float4*)&a[4] = *(float4*)&As[kk][ty * 8 + 4];
      *(float4*)&bb[0] = *(float4*)&Bs[kk][tx * 8];
      *(float4*)&bb[4] = *(float4*)&Bs[kk][tx * 8 + 4];
      #pragma unroll
      for (int i = 0; i < 8; i++)
        #pragma unroll
        for (int j = 0; j < 8; j++) acc[i][j] = fmaf(a[i], bb[j], acc[i][j]);
    }
    __syncthreads();
  }
  if (SCATTER == 0) {
    #pragma unroll
    for (int i = 0; i < 8; i++) {
      int m = m0 + ty * 8 + i;
      if (m < M) {
        float bv = bias ? bias[m] : 0.f;
        float* p = Out + ((size_t)(b * M + m)) * Tt + t0 + tx * 8;
        *(float4*)p = make_float4(acc[i][0] + bv, acc[i][1] + bv, acc[i][2] + bv, acc[i][3] + bv);
        *(float4*)(p + 4) = make_float4(acc[i][4] + bv, acc[i][5] + bv, acc[i][6] + bv, acc[i][7] + bv);
      }
    }
  } else {
    #pragma unroll
    for (int j = 0; j < 8; j++) {
      int n = n0 + tx * 8 + j;
      int m = m0 + ty * 8;
      if (m < M) {
        float* p = Out + (size_t)n * M + m;
        if (m + 7 < M) {
          *(float4*)p = make_float4(acc[0][j], acc[1][j], acc[2][j], acc[3][j]);
          *(float4*)(p + 4) = make_float4(acc[4][j], acc[5][j], acc[6][j], acc[7][j]);
        } else {
          for (int i = 0; i < 8 && m + i < M; i++) p[i] = acc[i][j];
        }
      }
    }
  }
}

// ---------------- RVQ core (proven) ----------------
__global__ __launch_bounds__(256) void rvq_kernel(const float* __restrict__ codebooks,
                                                  const float* __restrict__ e0t,
                                                  const float* __restrict__ cbsW,
                                                  const float* __restrict__ ptW,
                                                  const float* __restrict__ beffW,
                                                  float* __restrict__ Qout,
                                                  float* __restrict__ codesOut,
                                                  float* __restrict__ lossPart) {
  __shared__ float cbv[8][1024];
  __shared__ float cbs2[2][1024];
  __shared__ float Pt[36 * 65];
  __shared__ float est[16][72];
  __shared__ float lred[4];
  int tid = threadIdx.x, wid = tid >> 6, lane = tid & 63;
  int nb0 = blockIdx.x * 16;
  for (int idx = tid; idx < 2340; idx += 256) Pt[idx] = ptW[idx];
  for (int idx = tid; idx < 16 * 72; idx += 256)
    est[idx / 72][idx % 72] = e0t[(size_t)nb0 * 72 + idx] + beffW[idx % 72];
  float lossLocal = 0.f;

  for (int i = 0; i < NQ; i++) {
    __syncthreads();
    const float* cbg = codebooks + (size_t)i * CBS * CBD;
    for (int lin = tid; lin < 2048; lin += 256) {
      int j = lin >> 1, half = (lin & 1) << 2;
      float4 v = *(const float4*)(cbg + (size_t)j * 8 + half);
      cbv[half + 0][j] = v.x; cbv[half + 1][j] = v.y;
      cbv[half + 2][j] = v.z; cbv[half + 3][j] = v.w;
    }
    for (int lin = tid; lin < 1024; lin += 256) {
      cbs2[0][lin] = cbsW[((size_t)i * 2 + 0) * 1024 + lin];
      cbs2[1][lin] = cbsW[((size_t)i * 2 + 1) * 1024 + lin];
    }
    __syncthreads();

    float ze[4][8], en[4][8];
    #pragma unroll
    for (int w = 0; w < 4; w++) {
      int tokl = wid * 4 + w;
      float ss = 0.f;
      #pragma unroll
      for (int d = 0; d < 8; d++) { float v = est[tokl][i * 8 + d]; ze[w][d] = v; ss += v * v; }
      float inv = 1.0f / fmaxf(sqrtf(ss), EPSN);
      #pragma unroll
      for (int d = 0; d < 8; d++) en[w][d] = ze[w][d] * inv;
    }
    float best[4]; int bidx[4];
    #pragma unroll
    for (int w = 0; w < 4; w++) { best[w] = -INFINITY; bidx[w] = 0; }
    #pragma unroll 4
    for (int r = 0; r < 16; r++) {
      int j = lane + (r << 6);
      float c0 = cbv[0][j], c1 = cbv[1][j], c2 = cbv[2][j], c3 = cbv[3][j];
      float c4 = cbv[4][j], c5 = cbv[5][j], c6 = cbv[6][j], c7 = cbv[7][j];
      float ti = cbs2[0][j], ns = cbs2[1][j];
      #pragma unroll
      for (int w = 0; w < 4; w++) {
        float dt = en[w][0] * c0;
        dt = fmaf(en[w][1], c1, dt); dt = fmaf(en[w][2], c2, dt);
        dt = fmaf(en[w][3], c3, dt); dt = fmaf(en[w][4], c4, dt);
        dt = fmaf(en[w][5], c5, dt); dt = fmaf(en[w][6], c6, dt);
        dt = fmaf(en[w][7], c7, dt);
        float s = fmaf(dt, ti, -ns);
        if (s > best[w]) { best[w] = s; bidx[w] = j; }
      }
    }
    #pragma unroll
    for (int w = 0; w < 4; w++) {
      #pragma unroll
      for (int off = 32; off; off >>= 1) {
        float so = __shfl_xor(best[w], off);
        int jo = __shfl_xor(bidx[w], off);
        if (so > best[w] || (so == best[w] && jo < bidx[w])) { best[w] = so; bidx[w] = jo; }
      }
    }
    int d = lane & 7;
    #pragma unroll
    for (int w = 0; w < 4; w++) {
      int jstar = bidx[w];
      int tokl = wid * 4 + w;
      int n = nb0 + tokl;
      float qd = cbv[d][jstar];
      float diff = ze[w][d] - qd;
      float sq = diff * diff;
      sq += __shfl_xor(sq, 1); sq += __shfl_xor(sq, 2); sq += __shfl_xor(sq, 4);
      if (lane == 0) lossLocal += sq;
      if (lane < 8) Qout[(size_t)(i * 8 + lane) * NTOK + n] = qd;
      if (lane == 0) codesOut[(size_t)((n >> 11) * NQ + i) * TQ + (n & (TQ - 1))] = (float)jstar;
      if (i < NQ - 1) {
        int f = lane >> 3, d2 = lane & 7;
        int ip = i + 1 + f;
        if (ip < NQ) {
          int tri = (ip * (ip - 1)) / 2 + i;
          const float* prow = &Pt[tri * 65 + d2 * 8];
          float s = 0.f;
          #pragma unroll
          for (int dp = 0; dp < 8; dp++) s = fmaf(prow[dp], cbv[dp][jstar], s);
          est[tokl][ip * 8 + d2] -= s;
        }
      }
    }
  }
  if (lane == 0) lred[wid] = lossLocal;
  __syncthreads();
  if (tid == 0) {
    float s = ((lred[0] + lred[1]) + lred[2]) + lred[3];
    lossPart[blockIdx.x] = s;
  }
}

__global__ void loss_fin(const float* __restrict__ lossPart, float* __restrict__ out) {
  __shared__ float s[256];
  int tid = threadIdx.x;
  float v = 0.f;
  for (int r = 0; r < 4; r++) v += lossPart[tid + r * 256];
  s[tid] = v;
  __syncthreads();
  for (int w = 128; w; w >>= 1) {
    if (tid < w) s[tid] += s[tid + w];
    __syncthreads();
  }
  if (tid == 0) {
    float total = s[0] / 131072.0f;
    out[0] = total;
    out[1] = total;
  }
}

// ---------------- launch ----------------
extern "C" void kernel_launch(void* const* d_in, const int* in_sizes, int n_in,
                              void* d_out, int out_size, void* d_ws, size_t ws_size,
                              hipStream_t stream) {
  const float* z      = (const float*)d_in[0];
  const float* down_w = (const float*)d_in[1];
  const float* down_b = (const float*)d_in[2];
  const float* up_w   = (const float*)d_in[3];
  const float* up_b   = (const float*)d_in[4];
  const float* in_v   = (const float*)d_in[5];
  const float* in_g   = (const float*)d_in[6];
  const float* in_b   = (const float*)d_in[7];
  const float* out_v  = (const float*)d_in[8];
  const float* out_g  = (const float*)d_in[9];
  const float* out_b  = (const float*)d_in[10];
  const float* codebooks = (const float*)d_in[11];
  float* ws = (float*)d_ws;
  float* xout = (float*)d_out;
  float* codesOut = xout + (size_t)8 * 512 * 8192;
  float* lossOut = codesOut + (size_t)8 * NQ * TQ;
  const u16* dwp = (const u16*)(ws + OFF_DWP);
  const u16* uwp = (const u16*)(ws + OFF_UWP);

  hipLaunchKernelGGL(prep_wp, dim3(8192), dim3(256), 0, stream, down_w, up_w, ws);
  hipLaunchKernelGGL(prep_small1, dim3(74), dim3(256), 0, stream,
                     in_v, in_g, out_v, out_g, out_b, codebooks, ws);
  hipLaunchKernelGGL(prep2, dim3(594), dim3(256), 0, stream, in_b, out_b, ws);
  // down1: A=dwp[l=0] planes, B=z gather -> Z2 deinterleaved [1024][16384]
  hipLaunchKernelGGL((gemmT<3, 0, 0>), dim3(256, 4), dim3(256), 0, stream,
                     dwp, z, down_b, ws + OFF_Z2, 1024, 32768);
  // down2: A=dwp[l=1], B=Z2 rows -> x2 [8][512][2048]
  hipLaunchKernelGGL((gemmT<3, 2, 1>), dim3(128, 4), dim3(256), 0, stream,
                     dwp + (size_t)3 * ASTR, ws + OFF_Z2, down_b + 512, ws + OFF_X2, 1024, 16384);
  // e0 (fp32): WinN[72,512] @ x2 -> e0t [16384][72]
  hipLaunchKernelGGL((gemm_conv<1, 1>), dim3(128, 1), dim3(256), 0, stream,
                     ws + OFF_WINN, ws + OFF_X2, (const float*)nullptr, ws + OFF_E0T, 72, 512, 16384, 2048);
  // RVQ
  hipLaunchKernelGGL(rvq_kernel, dim3(1024), dim3(256), 0, stream,
                     codebooks, ws + OFF_E0T, ws + OFF_CBS, ws + OFF_PT, ws + OFF_BEFF,
                     ws + OFF_Q, codesOut, ws + OFF_LOSS);
  // zq (fp32, K=72): WoutS @ Q + bsum -> zqf [512][16384]
  hipLaunchKernelGGL((gemm_conv<2, 0>), dim3(128, 4), dim3(256), 0, stream,
                     ws + OFF_WOUT, ws + OFF_Q, ws + OFF_BSUM, ws + OFF_ZQF, 512, 72, 16384, 16384);
  // up1: A=uwp[l=0], B=zqf rows -> U2 [512][32768]
  hipLaunchKernelGGL((gemmT<2, 2, 2>), dim3(128, 8), dim3(256), 0, stream,
                     uwp, ws + OFF_ZQF, up_b, ws + OFF_U2, 512, 16384);
  // up2: A=uwp[l=1], B=U2 rows -> x fp32 to d_out
  hipLaunchKernelGGL((gemmT<2, 2, 3>), dim3(256, 8), dim3(256), 0, stream,
                     uwp + (size_t)2 * ASTR, ws + OFF_U2, up_b + 512, xout, 512, 32768);
  hipLaunchKernelGGL(loss_fin, dim3(1), dim3(256), 0, stream, ws + OFF_LOSS, lossOut);
}

// Round 10
// 1038.287 us; speedup vs baseline: 1.5410x; 1.0099x over previous
//
#include <hip/hip_runtime.h>
#include <math.h>

// FireflyVQ R10: gemmT v3 - swizzled n-major bf16 LDS planes (chunk XOR,
// bank-floor writes/reads), row-owner staging (coalesced scalar loads,
// split-once), reg prefetch. down1/down2 NS=3, up1/up2 NS=2.
// e0/zq fp32 gemm_conv; RVQ unchanged.

using u16 = unsigned short;
typedef __attribute__((ext_vector_type(8))) short bf16x8;
typedef __attribute__((ext_vector_type(8))) u16 su16x8;
typedef __attribute__((ext_vector_type(4))) float f32x4;

constexpr int NQ = 9, CBS = 1024, CBD = 8;
constexpr int TQ = 2048;
constexpr int NTOK = 16384;
constexpr int ASTR = 524288;   // u16 elems per weight plane
#define EPSN 1e-12f

// ---- ws layout (float offsets); aliases strictly stream-ordered (~111.5 MB)
constexpr size_t OFF_Z2   = 0;                         // Z2 [1024][16384]
constexpr size_t OFF_U2   = 0;                         // U2 [512][32768] (alias)
constexpr size_t OFF_Q    = 14417920;                  // Q [72][16384]
constexpr size_t OFF_E0T  = 15597568;                  // e0t [16384][72]
constexpr size_t OFF_X2   = 16777216;                  // x2 [8][512][2048]
constexpr size_t OFF_ZQF  = OFF_X2;                    // zqf [512][16384] (alias)
constexpr size_t OFF_DWP  = OFF_X2 + 8388608;          // 1,572,864 fl
constexpr size_t OFF_UWP  = OFF_DWP + 1572864;         // 1,048,576 fl
constexpr size_t OFF_WINN = OFF_UWP + 1048576;         // 36,864
constexpr size_t OFF_WOUT = OFF_WINN + 36864;          // 36,864
constexpr size_t OFF_CBS  = OFF_WOUT + 36864;          // 18,432
constexpr size_t OFF_PT   = OFF_CBS + 18432;           // 2,340
constexpr size_t OFF_BEFF = OFF_PT + 2340;             // 72
constexpr size_t OFF_BSUM = OFF_BEFF + 72;             // 512
constexpr size_t OFF_LOSS = OFF_BSUM + 512;            // 1,024

// ---------------- prep: weight planes (truncation split) ----------------
__global__ void prep_wp(const float* __restrict__ down_w, const float* __restrict__ up_w,
                        float* __restrict__ ws) {
  int idx = blockIdx.x * 256 + threadIdx.x;   // [0, 4*524288)
  int mat = idx >> 19, e = idx & 524287;
  if (mat < 2) {  // dwp[l][p][o][k=kap*512+i]
    int o = e >> 10, k = e & 1023, kap = k >> 9, i = k & 511;
    float v = down_w[((size_t)(mat * 512 + o) * 512 + i) * 2 + kap];
    u16* dst = (u16*)(ws + OFF_DWP) + (size_t)mat * 3 * ASTR;
    unsigned u = __float_as_uint(v);
    dst[e] = (u16)(u >> 16);
    float r = v - __uint_as_float(u & 0xFFFF0000u);
    unsigned ur = __float_as_uint(r);
    dst[ASTR + e] = (u16)(ur >> 16);
    float r2 = r - __uint_as_float(ur & 0xFFFF0000u);
    dst[2 * ASTR + e] = (u16)(__float_as_uint(r2) >> 16);
  } else {        // uwp[l][p][m=2o+kap][c]
    int l = mat - 2;
    int m = e >> 9, c = e & 511;
    float v = up_w[(size_t)l * 524288 + ((size_t)c * 512 + (m >> 1)) * 2 + (m & 1)];
    u16* dst = (u16*)(ws + OFF_UWP) + (size_t)l * 2 * ASTR;
    unsigned u = __float_as_uint(v);
    dst[e] = (u16)(u >> 16);
    float r = v - __uint_as_float(u & 0xFFFF0000u);
    dst[ASTR + e] = (u16)(__float_as_uint(r) >> 16);
  }
}

__global__ void prep_small1(const float* __restrict__ in_v, const float* __restrict__ in_g,
                            const float* __restrict__ out_v, const float* __restrict__ out_g,
                            const float* __restrict__ out_b, const float* __restrict__ codebooks,
                            float* __restrict__ ws) {
  int bid = blockIdx.x, tid = threadIdx.x;
  if (bid < 18) {
    int wid = bid * 4 + (tid >> 6), lane = tid & 63;
    if (wid < 72) {
      const float* v = in_v + (size_t)wid * 512;
      float ss = 0.f;
      for (int c = lane; c < 512; c += 64) ss += v[c] * v[c];
      #pragma unroll
      for (int o = 32; o; o >>= 1) ss += __shfl_xor(ss, o);
      float sc = in_g[wid] / sqrtf(ss);
      float* dst = ws + OFF_WINN + (size_t)wid * 512;
      for (int c = lane; c < 512; c += 64) dst[c] = v[c] * sc;
    }
  } else if (bid < 36) {
    int r = (bid - 18) * 256 + tid;
    if (r < 4608) {
      int i = r >> 9, c = r & 511;
      const float* v = out_v + (size_t)r * 8;
      float ss = 0.f;
      #pragma unroll
      for (int d = 0; d < 8; d++) ss += v[d] * v[d];
      float sc = out_g[r] / sqrtf(ss);
      float* dst = ws + OFF_WOUT + (size_t)c * 72 + i * 8;
      #pragma unroll
      for (int d = 0; d < 8; d++) dst[d] = v[d] * sc;
    }
  } else if (bid < 72) {
    int r = (bid - 36) * 256 + tid;
    if (r < 9216) {
      int i = r >> 10, j = r & 1023;
      const float* v = codebooks + (size_t)r * 8;
      float ss = 0.f;
      #pragma unroll
      for (int d = 0; d < 8; d++) ss += v[d] * v[d];
      float nm = fmaxf(sqrtf(ss), EPSN);
      float nsq = 0.f;
      #pragma unroll
      for (int d = 0; d < 8; d++) { float cn = v[d] / nm; nsq += cn * cn; }
      ws[OFF_CBS + ((size_t)i * 2 + 0) * 1024 + j] = 2.0f / nm;
      ws[OFF_CBS + ((size_t)i * 2 + 1) * 1024 + j] = nsq;
    }
  } else {
    int c = (bid - 72) * 256 + tid;
    if (c < 512) {
      float s = 0.f;
      #pragma unroll
      for (int j = 0; j < 9; j++) s += out_b[j * 512 + c];
      ws[OFF_BSUM + c] = s;
    }
  }
}

__global__ void prep2(const float* __restrict__ in_b, const float* __restrict__ out_b,
                      float* __restrict__ ws) {
  int gw = blockIdx.x * 4 + (threadIdx.x >> 6), lane = threadIdx.x & 63;
  const float* WinN = ws + OFF_WINN;
  const float* WoutS = ws + OFF_WOUT;
  if (gw < 2304) {
    int tri = gw >> 6, dd = gw & 63;
    int ip = 1;
    while (tri >= ip * (ip + 1) / 2) ip++;
    int i = tri - ip * (ip - 1) / 2;
    int d = dd >> 3, dp = dd & 7;
    const float* a = WinN + (size_t)(ip * 8 + d) * 512;
    float s = 0.f;
    for (int c = lane; c < 512; c += 64) s += a[c] * WoutS[(size_t)c * 72 + i * 8 + dp];
    #pragma unroll
    for (int o = 32; o; o >>= 1) s += __shfl_xor(s, o);
    if (lane == 0) ws[OFF_PT + (size_t)tri * 65 + dd] = s;
  } else if (gw < 2376) {
    int r = gw - 2304;
    int i = r >> 3;
    const float* a = WinN + (size_t)r * 512;
    float s = 0.f;
    for (int c = lane; c < 512; c += 64) {
      float ob = 0.f;
      for (int j = 0; j < i; j++) ob += out_b[j * 512 + c];
      s += a[c] * ob;
    }
    #pragma unroll
    for (int o = 32; o; o >>= 1) s += __shfl_xor(s, o);
    if (lane == 0) ws[OFF_BEFF + r] = in_b[r] - s;
  }
}

// ---------------- gemmT v3 ----------------
// Tile 128m x 128n, BK=32, 4 waves (2x2). A: pre-split u16 planes [M][K].
// B LDS: Bp[NS][128 rows(n)][32 u16(k)]; 16B chunk swizzle c' = c ^ ((n>>1)&3)
//   -> both stage-writes and frag-reads hit the 64-lane b128 bank floor.
// Staging: thread owns row n = tid&127, k-half kw = tid>>7 (16 k):
//   16 scalar global loads (lane-consecutive n -> coalesced), split once,
//   2 b128 writes per plane. Reg prefetch of next tile before compute.
// GM 0: down1 z-gather [b][512][8192] (stride-2); GM 2: plain rows [K][N].
// EPI 0: down1 -> Z2[(t1&1)*512+o][b*2048+(t1>>1)] + bias[o]   (b=n>>12)
// EPI 1: down2 -> x2[((b<<9)+o)*2048+t] + bias[o]              (b=n>>11)
// EPI 2: up1   -> U2[o][b*4096+2t+kap] + bias[o] float2        (b=n>>11)
// EPI 3: up2   -> x[((b<<9)+o)*8192+2*t1+kap] + bias[o] float2 (b=n>>12)
template <int NS, int GM, int EPI>
__global__ __launch_bounds__(256) void gemmT(const u16* __restrict__ Ap,
                                             const float* __restrict__ Bsrc,
                                             const float* __restrict__ bias,
                                             float* __restrict__ Out,
                                             int K, int N) {
  __shared__ u16 Bp[NS][128][32];
  const int tid = threadIdx.x;
  const int w = tid >> 6, l = tid & 63;
  const int g = l >> 4, li = l & 15;
  const int wr = w >> 1, wc = w & 1;
  const int n0 = blockIdx.x * 128, m0 = blockIdx.y * 128;
  const int nn = tid & 127, kw = tid >> 7;
  const int bb = n0 >> 12;                 // GM0 only
  const int tb = (n0 & 4095) + nn;         // GM0 only

  f32x4 acc[4][4];
  #pragma unroll
  for (int a = 0; a < 4; a++)
    #pragma unroll
    for (int b = 0; b < 4; b++) acc[a][b] = (f32x4){0.f, 0.f, 0.f, 0.f};

  float prv[16];

#define LOADB(K0)                                                              \
  _Pragma("unroll")                                                            \
  for (int j_ = 0; j_ < 16; ++j_) {                                            \
    int k_ = (K0) + kw * 16 + j_;                                              \
    if constexpr (GM == 0) {                                                   \
      int kap_ = k_ >> 9, ich_ = k_ & 511;                                     \
      prv[j_] = Bsrc[((size_t)(bb * 512 + ich_) << 13) + 2 * tb + kap_];       \
    } else {                                                                   \
      prv[j_] = Bsrc[(size_t)k_ * N + n0 + nn];                                \
    }                                                                          \
  }

  LOADB(0)

  const int sw = (nn >> 1) & 3;
  const int c0 = (((2 * kw) ^ sw) << 3), c1 = (((2 * kw + 1) ^ sw) << 3);

  for (int k0 = 0; k0 < K; k0 += 32) {
    __syncthreads();
    // ---- split prv -> swizzled LDS planes
    {
      su16x8 pa[NS], pb[NS];
      #pragma unroll
      for (int j = 0; j < 8; ++j) {
        {
          float v = prv[j];
          unsigned u = __float_as_uint(v);
          pa[0][j] = (u16)(u >> 16);
          float r = v - __uint_as_float(u & 0xFFFF0000u);
          unsigned ur = __float_as_uint(r);
          pa[1][j] = (u16)(ur >> 16);
          if constexpr (NS == 3) {
            float r2 = r - __uint_as_float(ur & 0xFFFF0000u);
            pa[2][j] = (u16)(__float_as_uint(r2) >> 16);
          }
        }
        {
          float v = prv[8 + j];
          unsigned u = __float_as_uint(v);
          pb[0][j] = (u16)(u >> 16);
          float r = v - __uint_as_float(u & 0xFFFF0000u);
          unsigned ur = __float_as_uint(r);
          pb[1][j] = (u16)(ur >> 16);
          if constexpr (NS == 3) {
            float r2 = r - __uint_as_float(ur & 0xFFFF0000u);
            pb[2][j] = (u16)(__float_as_uint(r2) >> 16);
          }
        }
      }
      #pragma unroll
      for (int p = 0; p < NS; ++p) {
        *(su16x8*)&Bp[p][nn][c0] = pa[p];
        *(su16x8*)&Bp[p][nn][c1] = pb[p];
      }
    }
    __syncthreads();
    if (k0 + 32 < K) { LOADB(k0 + 32) }

    // ---- fragments + MFMA
    bf16x8 bfr[4][NS];
    #pragma unroll
    for (int fn = 0; fn < 4; ++fn) {
      int row = wc * 64 + fn * 16 + li;
      int cs = ((g ^ ((row >> 1) & 3)) << 3);
      #pragma unroll
      for (int q = 0; q < NS; ++q)
        bfr[fn][q] = *(const bf16x8*)&Bp[q][row][cs];
    }
    const u16* arow = Ap + (size_t)(m0 + wr * 64 + li) * K + k0 + g * 8;
    #pragma unroll
    for (int fm = 0; fm < 4; ++fm) {
      bf16x8 afr[NS];
      #pragma unroll
      for (int p = 0; p < NS; ++p)
        afr[p] = *(const bf16x8*)(arow + (size_t)p * ASTR + (size_t)fm * 16 * K);
      #pragma unroll
      for (int fn = 0; fn < 4; ++fn) {
        f32x4 a = acc[fm][fn];
        if constexpr (NS == 3) {
          a = __builtin_amdgcn_mfma_f32_16x16x32_bf16(afr[2], bfr[fn][0], a, 0, 0, 0);
          a = __builtin_amdgcn_mfma_f32_16x16x32_bf16(afr[1], bfr[fn][1], a, 0, 0, 0);
          a = __builtin_amdgcn_mfma_f32_16x16x32_bf16(afr[0], bfr[fn][2], a, 0, 0, 0);
          a = __builtin_amdgcn_mfma_f32_16x16x32_bf16(afr[1], bfr[fn][0], a, 0, 0, 0);
          a = __builtin_amdgcn_mfma_f32_16x16x32_bf16(afr[0], bfr[fn][1], a, 0, 0, 0);
          a = __builtin_amdgcn_mfma_f32_16x16x32_bf16(afr[0], bfr[fn][0], a, 0, 0, 0);
        } else {
          a = __builtin_amdgcn_mfma_f32_16x16x32_bf16(afr[1], bfr[fn][0], a, 0, 0, 0);
          a = __builtin_amdgcn_mfma_f32_16x16x32_bf16(afr[0], bfr[fn][1], a, 0, 0, 0);
          a = __builtin_amdgcn_mfma_f32_16x16x32_bf16(afr[0], bfr[fn][0], a, 0, 0, 0);
        }
        acc[fm][fn] = a;
      }
    }
  }
#undef LOADB

  // ---- epilogue
  const int mb = m0 + wr * 64 + g * 4;
  const int nb = n0 + wc * 64 + li;
  if constexpr (EPI == 0) {
    #pragma unroll
    for (int fn = 0; fn < 4; ++fn) {
      int n = nb + fn * 16;
      int b = n >> 12, t1 = n & 4095;
      size_t col = (size_t)b * 2048 + (t1 >> 1);
      int rowbase = (t1 & 1) * 512;
      #pragma unroll
      for (int fm = 0; fm < 4; ++fm)
        #pragma unroll
        for (int r = 0; r < 4; ++r) {
          int o = mb + fm * 16 + r;
          Out[(size_t)(rowbase + o) * 16384 + col] = acc[fm][fn][r] + bias[o];
        }
    }
  } else if constexpr (EPI == 1) {
    #pragma unroll
    for (int fn = 0; fn < 4; ++fn) {
      int n = nb + fn * 16;
      int b = n >> 11, t = n & 2047;
      #pragma unroll
      for (int fm = 0; fm < 4; ++fm)
        #pragma unroll
        for (int r = 0; r < 4; ++r) {
          int o = mb + fm * 16 + r;
          Out[((size_t)((b << 9) + o)) * 2048 + t] = acc[fm][fn][r] + bias[o];
        }
    }
  } else if constexpr (EPI == 2) {
    #pragma unroll
    for (int fn = 0; fn < 4; ++fn) {
      int n = nb + fn * 16;
      int b = n >> 11, t = n & 2047;
      #pragma unroll
      for (int fm = 0; fm < 4; ++fm)
        #pragma unroll
        for (int rp = 0; rp < 2; ++rp) {
          int m2 = mb + fm * 16 + 2 * rp;
          int o = m2 >> 1;
          float bv = bias[o];
          float2 st = make_float2(acc[fm][fn][2 * rp] + bv, acc[fm][fn][2 * rp + 1] + bv);
          *(float2*)&Out[(size_t)o * 32768 + (size_t)b * 4096 + 2 * t] = st;
        }
    }
  } else {  // EPI == 3
    #pragma unroll
    for (int fn = 0; fn < 4; ++fn) {
      int n = nb + fn * 16;
      int b = n >> 12, t1 = n & 4095;
      #pragma unroll
      for (int fm = 0; fm < 4; ++fm)
        #pragma unroll
        for (int rp = 0; rp < 2; ++rp) {
          int m2 = mb + fm * 16 + 2 * rp;
          int o = m2 >> 1;
          float bv = bias[o];
          float2 st = make_float2(acc[fm][fn][2 * rp] + bv, acc[fm][fn][2 * rp + 1] + bv);
          *(float2*)&Out[((size_t)((b << 9) + o)) * 8192 + 2 * t1] = st;
        }
    }
  }
}

// ---------------- proven fp32 tiled GEMM (e0, zq) ----------------
template <int GATHER, int SCATTER>
__global__ __launch_bounds__(256) void gemm_conv(const float* __restrict__ A,
                                                 const float* __restrict__ Bsrc,
                                                 const float* __restrict__ bias,
                                                 float* __restrict__ Out,
                                                 int M, int K, int N, int Tt) {
  constexpr int BM = 128, BN = 128, BK = 16;
  __shared__ float As[BK][BM + 4];
  __shared__ float Bs[BK][BN + 4];
  int tid = threadIdx.x;
  int tx = tid & 15, ty = tid >> 4;
  int n0 = blockIdx.x * BN, m0 = blockIdx.y * BM;
  int b = n0 / Tt, t0 = n0 % Tt;
  float acc[8][8];
  #pragma unroll
  for (int i = 0; i < 8; i++)
    #pragma unroll
    for (int j = 0; j < 8; j++) acc[i][j] = 0.f;

  for (int k0 = 0; k0 < K; k0 += BK) {
    #pragma unroll
    for (int rep = 0; rep < 2; rep++) {
      int f = tid + rep * 256;
      int row = f >> 2, c4 = (f & 3) << 2;
      int m = m0 + row, k = k0 + c4;
      float4 v = make_float4(0.f, 0.f, 0.f, 0.f);
      if (m < M) {
        if (k + 3 < K) {
          v = *(const float4*)(A + (size_t)m * K + k);
        } else {
          float tmp[4] = {0.f, 0.f, 0.f, 0.f};
          for (int c = 0; c < 4; c++)
            if (k + c < K) tmp[c] = A[(size_t)m * K + k + c];
          v = make_float4(tmp[0], tmp[1], tmp[2], tmp[3]);
        }
      }
      As[c4 + 0][row] = v.x; As[c4 + 1][row] = v.y;
      As[c4 + 2][row] = v.z; As[c4 + 3][row] = v.w;
    }
    #pragma unroll
    for (int rep = 0; rep < 2; rep++) {
      int f = tid + rep * 256;
      int kk = f >> 5, n4 = (f & 31) << 2;
      int k = k0 + kk;
      float4 v = make_float4(0.f, 0.f, 0.f, 0.f);
      if (GATHER == 1) {
        v = *(const float4*)(Bsrc + ((size_t)(b * K + k)) * Tt + t0 + n4);
      } else {
        if (k < K) v = *(const float4*)(Bsrc + (size_t)k * N + n0 + n4);
      }
      *(float4*)&Bs[kk][n4] = v;
    }
    __syncthreads();
    #pragma unroll
    for (int kk = 0; kk < BK; kk++) {
      float a[8], bb[8];
      *(float4*)&a[0] = *(float4*)&As[kk][ty * 8];
      *(float4*)&a[4] = *(float4*)&As[kk][ty * 8 + 4];
      *(float4*)&bb[0] = *(float4*)&Bs[kk][tx * 8];
      *(float4*)&bb[4] = *(float4*)&Bs[kk][tx * 8 + 4];
      #pragma unroll
      for (int i = 0; i < 8; i++)
        #pragma unroll
        for (int j = 0; j < 8; j++) acc[i][j] = fmaf(a[i], bb[j], acc[i][j]);
    }
    __syncthreads();
  }
  if (SCATTER == 0) {
    #pragma unroll
    for (int i = 0; i < 8; i++) {
      int m = m0 + ty * 8 + i;
      if (m < M) {
        float bv = bias ? bias[m] : 0.f;
        float* p = Out + ((size_t)(b * M + m)) * Tt + t0 + tx * 8;
        *(float4*)p = make_float4(acc[i][0] + bv, acc[i][1] + bv, acc[i][2] + bv, acc[i][3] + bv);
        *(float4*)(p + 4) = make_float4(acc[i][4] + bv, acc[i][5] + bv, acc[i][6] + bv, acc[i][7] + bv);
      }
    }
  } else {
    #pragma unroll
    for (int j = 0; j < 8; j++) {
      int n = n0 + tx * 8 + j;
      int m = m0 + ty * 8;
      if (m < M) {
        float* p = Out + (size_t)n * M + m;
        if (m + 7 < M) {
          *(float4*)p = make_float4(acc[0][j], acc[1][j], acc[2][j], acc[3][j]);
          *(float4*)(p + 4) = make_float4(acc[4][j], acc[5][j], acc[6][j], acc[7][j]);
        } else {
          for (int i = 0; i < 8 && m + i < M; i++) p[i] = acc[i][j];
        }
      }
    }
  }
}

// ---------------- RVQ core (proven) ----------------
__global__ __launch_bounds__(256) void rvq_kernel(const float* __restrict__ codebooks,
                                                  const float* __restrict__ e0t,
                                                  const float* __restrict__ cbsW,
                                                  const float* __restrict__ ptW,
                                                  const float* __restrict__ beffW,
                                                  float* __restrict__ Qout,
                                                  float* __restrict__ codesOut,
                                                  float* __restrict__ lossPart) {
  __shared__ float cbv[8][1024];
  __shared__ float cbs2[2][1024];
  __shared__ float Pt[36 * 65];
  __shared__ float est[16][72];
  __shared__ float lred[4];
  int tid = threadIdx.x, wid = tid >> 6, lane = tid & 63;
  int nb0 = blockIdx.x * 16;
  for (int idx = tid; idx < 2340; idx += 256) Pt[idx] = ptW[idx];
  for (int idx = tid; idx < 16 * 72; idx += 256)
    est[idx / 72][idx % 72] = e0t[(size_t)nb0 * 72 + idx] + beffW[idx % 72];
  float lossLocal = 0.f;

  for (int i = 0; i < NQ; i++) {
    __syncthreads();
    const float* cbg = codebooks + (size_t)i * CBS * CBD;
    for (int lin = tid; lin < 2048; lin += 256) {
      int j = lin >> 1, half = (lin & 1) << 2;
      float4 v = *(const float4*)(cbg + (size_t)j * 8 + half);
      cbv[half + 0][j] = v.x; cbv[half + 1][j] = v.y;
      cbv[half + 2][j] = v.z; cbv[half + 3][j] = v.w;
    }
    for (int lin = tid; lin < 1024; lin += 256) {
      cbs2[0][lin] = cbsW[((size_t)i * 2 + 0) * 1024 + lin];
      cbs2[1][lin] = cbsW[((size_t)i * 2 + 1) * 1024 + lin];
    }
    __syncthreads();

    float ze[4][8], en[4][8];
    #pragma unroll
    for (int w = 0; w < 4; w++) {
      int tokl = wid * 4 + w;
      float ss = 0.f;
      #pragma unroll
      for (int d = 0; d < 8; d++) { float v = est[tokl][i * 8 + d]; ze[w][d] = v; ss += v * v; }
      float inv = 1.0f / fmaxf(sqrtf(ss), EPSN);
      #pragma unroll
      for (int d = 0; d < 8; d++) en[w][d] = ze[w][d] * inv;
    }
    float best[4]; int bidx[4];
    #pragma unroll
    for (int w = 0; w < 4; w++) { best[w] = -INFINITY; bidx[w] = 0; }
    #pragma unroll 4
    for (int r = 0; r < 16; r++) {
      int j = lane + (r << 6);
      float c0 = cbv[0][j], c1 = cbv[1][j], c2 = cbv[2][j], c3 = cbv[3][j];
      float c4 = cbv[4][j], c5 = cbv[5][j], c6 = cbv[6][j], c7 = cbv[7][j];
      float ti = cbs2[0][j], ns = cbs2[1][j];
      #pragma unroll
      for (int w = 0; w < 4; w++) {
        float dt = en[w][0] * c0;
        dt = fmaf(en[w][1], c1, dt); dt = fmaf(en[w][2], c2, dt);
        dt = fmaf(en[w][3], c3, dt); dt = fmaf(en[w][4], c4, dt);
        dt = fmaf(en[w][5], c5, dt); dt = fmaf(en[w][6], c6, dt);
        dt = fmaf(en[w][7], c7, dt);
        float s = fmaf(dt, ti, -ns);
        if (s > best[w]) { best[w] = s; bidx[w] = j; }
      }
    }
    #pragma unroll
    for (int w = 0; w < 4; w++) {
      #pragma unroll
      for (int off = 32; off; off >>= 1) {
        float so = __shfl_xor(best[w], off);
        int jo = __shfl_xor(bidx[w], off);
        if (so > best[w] || (so == best[w] && jo < bidx[w])) { best[w] = so; bidx[w] = jo; }
      }
    }
    int d = lane & 7;
    #pragma unroll
    for (int w = 0; w < 4; w++) {
      int jstar = bidx[w];
      int tokl = wid * 4 + w;
      int n = nb0 + tokl;
      float qd = cbv[d][jstar];
      float diff = ze[w][d] - qd;
      float sq = diff * diff;
      sq += __shfl_xor(sq, 1); sq += __shfl_xor(sq, 2); sq += __shfl_xor(sq, 4);
      if (lane == 0) lossLocal += sq;
      if (lane < 8) Qout[(size_t)(i * 8 + lane) * NTOK + n] = qd;
      if (lane == 0) codesOut[(size_t)((n >> 11) * NQ + i) * TQ + (n & (TQ - 1))] = (float)jstar;
      if (i < NQ - 1) {
        int f = lane >> 3, d2 = lane & 7;
        int ip = i + 1 + f;
        if (ip < NQ) {
          int tri = (ip * (ip - 1)) / 2 + i;
          const float* prow = &Pt[tri * 65 + d2 * 8];
          float s = 0.f;
          #pragma unroll
          for (int dp = 0; dp < 8; dp++) s = fmaf(prow[dp], cbv[dp][jstar], s);
          est[tokl][ip * 8 + d2] -= s;
        }
      }
    }
  }
  if (lane == 0) lred[wid] = lossLocal;
  __syncthreads();
  if (tid == 0) {
    float s = ((lred[0] + lred[1]) + lred[2]) + lred[3];
    lossPart[blockIdx.x] = s;
  }
}

__global__ void loss_fin(const float* __restrict__ lossPart, float* __restrict__ out) {
  __shared__ float s[256];
  int tid = threadIdx.x;
  float v = 0.f;
  for (int r = 0; r < 4; r++) v += lossPart[tid + r * 256];
  s[tid] = v;
  __syncthreads();
  for (int w = 128; w; w >>= 1) {
    if (tid < w) s[tid] += s[tid + w];
    __syncthreads();
  }
  if (tid == 0) {
    float total = s[0] / 131072.0f;
    out[0] = total;
    out[1] = total;
  }
}

// ---------------- launch ----------------
extern "C" void kernel_launch(void* const* d_in, const int* in_sizes, int n_in,
                              void* d_out, int out_size, void* d_ws, size_t ws_size,
                              hipStream_t stream) {
  const float* z      = (const float*)d_in[0];
  const float* down_w = (const float*)d_in[1];
  const float* down_b = (const float*)d_in[2];
  const float* up_w   = (const float*)d_in[3];
  const float* up_b   = (const float*)d_in[4];
  const float* in_v   = (const float*)d_in[5];
  const float* in_g   = (const float*)d_in[6];
  const float* in_b   = (const float*)d_in[7];
  const float* out_v  = (const float*)d_in[8];
  const float* out_g  = (const float*)d_in[9];
  const float* out_b  = (const float*)d_in[10];
  const float* codebooks = (const float*)d_in[11];
  float* ws = (float*)d_ws;
  float* xout = (float*)d_out;
  float* codesOut = xout + (size_t)8 * 512 * 8192;
  float* lossOut = codesOut + (size_t)8 * NQ * TQ;
  const u16* dwp = (const u16*)(ws + OFF_DWP);
  const u16* uwp = (const u16*)(ws + OFF_UWP);

  hipLaunchKernelGGL(prep_wp, dim3(8192), dim3(256), 0, stream, down_w, up_w, ws);
  hipLaunchKernelGGL(prep_small1, dim3(74), dim3(256), 0, stream,
                     in_v, in_g, out_v, out_g, out_b, codebooks, ws);
  hipLaunchKernelGGL(prep2, dim3(594), dim3(256), 0, stream, in_b, out_b, ws);
  // down1: A=dwp[l=0] planes, B=z gather -> Z2 deinterleaved [1024][16384]
  hipLaunchKernelGGL((gemmT<3, 0, 0>), dim3(256, 4), dim3(256), 0, stream,
                     dwp, z, down_b, ws + OFF_Z2, 1024, 32768);
  // down2: A=dwp[l=1], B=Z2 rows -> x2 [8][512][2048]
  hipLaunchKernelGGL((gemmT<3, 2, 1>), dim3(128, 4), dim3(256), 0, stream,
                     dwp + (size_t)3 * ASTR, ws + OFF_Z2, down_b + 512, ws + OFF_X2, 1024, 16384);
  // e0 (fp32): WinN[72,512] @ x2 -> e0t [16384][72]
  hipLaunchKernelGGL((gemm_conv<1, 1>), dim3(128, 1), dim3(256), 0, stream,
                     ws + OFF_WINN, ws + OFF_X2, (const float*)nullptr, ws + OFF_E0T, 72, 512, 16384, 2048);
  // RVQ
  hipLaunchKernelGGL(rvq_kernel, dim3(1024), dim3(256), 0, stream,
                     codebooks, ws + OFF_E0T, ws + OFF_CBS, ws + OFF_PT, ws + OFF_BEFF,
                     ws + OFF_Q, codesOut, ws + OFF_LOSS);
  // zq (fp32, K=72): WoutS @ Q + bsum -> zqf [512][16384]
  hipLaunchKernelGGL((gemm_conv<2, 0>), dim3(128, 4), dim3(256), 0, stream,
                     ws + OFF_WOUT, ws + OFF_Q, ws + OFF_BSUM, ws + OFF_ZQF, 512, 72, 16384, 16384);
  // up1: A=uwp[l=0], B=zqf rows -> U2 [512][32768]
  hipLaunchKernelGGL((gemmT<2, 2, 2>), dim3(128, 8), dim3(256), 0, stream,
                     uwp, ws + OFF_ZQF, up_b, ws + OFF_U2, 512, 16384);
  // up2: A=uwp[l=1], B=U2 rows -> x fp32 to d_out
  hipLaunchKernelGGL((gemmT<2, 2, 3>), dim3(256, 8), dim3(256), 0, stream,
                     uwp + (size_t)2 * ASTR, ws + OFF_U2, up_b + 512, xout, 512, 32768);
  hipLaunchKernelGGL(loss_fin, dim3(1), dim3(256), 0, stream, ws + OFF_LOSS, lossOut);
}

// Round 11
// 965.924 us; speedup vs baseline: 1.6565x; 1.0749x over previous
//
#include <hip/hip_runtime.h>
#include <math.h>

// FireflyVQ R11: gemmT v4 - LDS double-buffer (1 barrier/K-step), 2-tile-deep
// register prefetch (covers HBM latency), paired-kap float2 conv gathers,
// swizzled bf16 LDS planes (0 conflicts, from R10). down NS=3, up NS=2.
// e0/zq fp32 gemm_conv; RVQ unchanged.

using u16 = unsigned short;
typedef __attribute__((ext_vector_type(8))) short bf16x8;
typedef __attribute__((ext_vector_type(8))) u16 su16x8;
typedef __attribute__((ext_vector_type(4))) float f32x4;

constexpr int NQ = 9, CBS = 1024, CBD = 8;
constexpr int TQ = 2048;
constexpr int NTOK = 16384;
constexpr int ASTR = 524288;   // u16 elems per weight plane
#define EPSN 1e-12f

// ---- ws layout (float offsets); aliases strictly stream-ordered (~111.5 MB)
constexpr size_t OFF_X1   = 0;                         // x1 [512][32768]
constexpr size_t OFF_U2   = 0;                         // U2 [512][32768] (alias)
constexpr size_t OFF_Q    = 14417920;                  // Q [72][16384] (after x1 dead)
constexpr size_t OFF_E0T  = 15597568;                  // e0t [16384][72]
constexpr size_t OFF_X2   = 16777216;                  // x2 [8][512][2048]
constexpr size_t OFF_ZQF  = OFF_X2;                    // zqf [512][16384] (alias)
constexpr size_t OFF_DWP  = OFF_X2 + 8388608;          // 1,572,864 fl
constexpr size_t OFF_UWP  = OFF_DWP + 1572864;         // 1,048,576 fl
constexpr size_t OFF_WINN = OFF_UWP + 1048576;         // 36,864
constexpr size_t OFF_WOUT = OFF_WINN + 36864;          // 36,864
constexpr size_t OFF_CBS  = OFF_WOUT + 36864;          // 18,432
constexpr size_t OFF_PT   = OFF_CBS + 18432;           // 2,340
constexpr size_t OFF_BEFF = OFF_PT + 2340;             // 72
constexpr size_t OFF_BSUM = OFF_BEFF + 72;             // 512
constexpr size_t OFF_LOSS = OFF_BSUM + 512;            // 1,024

// ---------------- prep: weight planes (truncation split) ----------------
__global__ void prep_wp(const float* __restrict__ down_w, const float* __restrict__ up_w,
                        float* __restrict__ ws) {
  int idx = blockIdx.x * 256 + threadIdx.x;   // [0, 4*524288)
  int mat = idx >> 19, e = idx & 524287;
  if (mat < 2) {  // dwp[l][p][o][k'=2i+kap] == natural down_w flat order
    float v = down_w[(size_t)mat * 524288 + e];
    u16* dst = (u16*)(ws + OFF_DWP) + (size_t)mat * 3 * ASTR;
    unsigned u = __float_as_uint(v);
    dst[e] = (u16)(u >> 16);
    float r = v - __uint_as_float(u & 0xFFFF0000u);
    unsigned ur = __float_as_uint(r);
    dst[ASTR + e] = (u16)(ur >> 16);
    float r2 = r - __uint_as_float(ur & 0xFFFF0000u);
    dst[2 * ASTR + e] = (u16)(__float_as_uint(r2) >> 16);
  } else {        // uwp[l][p][m=2o+kap][c]
    int l = mat - 2;
    int m = e >> 9, c = e & 511;
    float v = up_w[(size_t)l * 524288 + ((size_t)c * 512 + (m >> 1)) * 2 + (m & 1)];
    u16* dst = (u16*)(ws + OFF_UWP) + (size_t)l * 2 * ASTR;
    unsigned u = __float_as_uint(v);
    dst[e] = (u16)(u >> 16);
    float r = v - __uint_as_float(u & 0xFFFF0000u);
    dst[ASTR + e] = (u16)(__float_as_uint(r) >> 16);
  }
}

__global__ void prep_small1(const float* __restrict__ in_v, const float* __restrict__ in_g,
                            const float* __restrict__ out_v, const float* __restrict__ out_g,
                            const float* __restrict__ out_b, const float* __restrict__ codebooks,
                            float* __restrict__ ws) {
  int bid = blockIdx.x, tid = threadIdx.x;
  if (bid < 18) {
    int wid = bid * 4 + (tid >> 6), lane = tid & 63;
    if (wid < 72) {
      const float* v = in_v + (size_t)wid * 512;
      float ss = 0.f;
      for (int c = lane; c < 512; c += 64) ss += v[c] * v[c];
      #pragma unroll
      for (int o = 32; o; o >>= 1) ss += __shfl_xor(ss, o);
      float sc = in_g[wid] / sqrtf(ss);
      float* dst = ws + OFF_WINN + (size_t)wid * 512;
      for (int c = lane; c < 512; c += 64) dst[c] = v[c] * sc;
    }
  } else if (bid < 36) {
    int r = (bid - 18) * 256 + tid;
    if (r < 4608) {
      int i = r >> 9, c = r & 511;
      const float* v = out_v + (size_t)r * 8;
      float ss = 0.f;
      #pragma unroll
      for (int d = 0; d < 8; d++) ss += v[d] * v[d];
      float sc = out_g[r] / sqrtf(ss);
      float* dst = ws + OFF_WOUT + (size_t)c * 72 + i * 8;
      #pragma unroll
      for (int d = 0; d < 8; d++) dst[d] = v[d] * sc;
    }
  } else if (bid < 72) {
    int r = (bid - 36) * 256 + tid;
    if (r < 9216) {
      int i = r >> 10, j = r & 1023;
      const float* v = codebooks + (size_t)r * 8;
      float ss = 0.f;
      #pragma unroll
      for (int d = 0; d < 8; d++) ss += v[d] * v[d];
      float nm = fmaxf(sqrtf(ss), EPSN);
      float nsq = 0.f;
      #pragma unroll
      for (int d = 0; d < 8; d++) { float cn = v[d] / nm; nsq += cn * cn; }
      ws[OFF_CBS + ((size_t)i * 2 + 0) * 1024 + j] = 2.0f / nm;
      ws[OFF_CBS + ((size_t)i * 2 + 1) * 1024 + j] = nsq;
    }
  } else {
    int c = (bid - 72) * 256 + tid;
    if (c < 512) {
      float s = 0.f;
      #pragma unroll
      for (int j = 0; j < 9; j++) s += out_b[j * 512 + c];
      ws[OFF_BSUM + c] = s;
    }
  }
}

__global__ void prep2(const float* __restrict__ in_b, const float* __restrict__ out_b,
                      float* __restrict__ ws) {
  int gw = blockIdx.x * 4 + (threadIdx.x >> 6), lane = threadIdx.x & 63;
  const float* WinN = ws + OFF_WINN;
  const float* WoutS = ws + OFF_WOUT;
  if (gw < 2304) {
    int tri = gw >> 6, dd = gw & 63;
    int ip = 1;
    while (tri >= ip * (ip + 1) / 2) ip++;
    int i = tri - ip * (ip - 1) / 2;
    int d = dd >> 3, dp = dd & 7;
    const float* a = WinN + (size_t)(ip * 8 + d) * 512;
    float s = 0.f;
    for (int c = lane; c < 512; c += 64) s += a[c] * WoutS[(size_t)c * 72 + i * 8 + dp];
    #pragma unroll
    for (int o = 32; o; o >>= 1) s += __shfl_xor(s, o);
    if (lane == 0) ws[OFF_PT + (size_t)tri * 65 + dd] = s;
  } else if (gw < 2376) {
    int r = gw - 2304;
    int i = r >> 3;
    const float* a = WinN + (size_t)r * 512;
    float s = 0.f;
    for (int c = lane; c < 512; c += 64) {
      float ob = 0.f;
      for (int j = 0; j < i; j++) ob += out_b[j * 512 + c];
      s += a[c] * ob;
    }
    #pragma unroll
    for (int o = 32; o; o >>= 1) s += __shfl_xor(s, o);
    if (lane == 0) ws[OFF_BEFF + r] = in_b[r] - s;
  }
}

// ---------------- gemmT v4 ----------------
// Tile 128m x 128n, BK=32, 4 waves (2x2). A: pre-split u16 planes [M][K'].
// LDS: Bp[2 dbuf][NS][128 n][32 k'] with 16B-chunk swizzle c^=((n>>1)&3).
// One barrier per K-step; prv loads issued 2-3 tiles ahead (pvA/pvB sets).
// GM 0: down1 paired gather z[(b*512+i)*8192 + 2t + kap] (float2)
// GM 1: down2 paired gather x1[i*32768 + b*4096 + 2t + kap] (float2)
// GM 2: plain rows Bsrc[k*N + n] (scalar, per-instr coalesced)
// EPI 0: x1[o*32768 + n] + bias[o]
// EPI 1: x2[((b<<9)+o)*2048 + t] + bias[o]            (b=n>>11)
// EPI 2: U2[o*32768 + b*4096 + 2t + kap] + bias[o]    (b=n>>11, float2)
// EPI 3: x[((b<<9)+o)*8192 + 2t1 + kap] + bias[o]     (b=n>>12, float2)
template <int NS, int GM, int EPI>
__global__ __launch_bounds__(256) void gemmT(const u16* __restrict__ Ap,
                                             const float* __restrict__ Bsrc,
                                             const float* __restrict__ bias,
                                             float* __restrict__ Out,
                                             int K, int N) {
  __shared__ u16 Bp[2][NS][128][32];
  const int tid = threadIdx.x;
  const int w = tid >> 6, l = tid & 63;
  const int g = l >> 4, li = l & 15;
  const int wr = w >> 1, wc = w & 1;
  const int n0 = blockIdx.x * 128, m0 = blockIdx.y * 128;
  const int nn = tid & 127, kw = tid >> 7;
  const int bb = (GM == 0) ? (n0 >> 12) : (n0 >> 11);
  const int tb = (GM == 0) ? ((n0 & 4095) + nn) : ((n0 & 2047) + nn);

  f32x4 acc[4][4];
  #pragma unroll
  for (int a = 0; a < 4; a++)
    #pragma unroll
    for (int b = 0; b < 4; b++) acc[a][b] = (f32x4){0.f, 0.f, 0.f, 0.f};

  float pvA[16], pvB[16];

#define LOADB(PV, K0)                                                           \
  if constexpr (GM == 0) {                                                      \
    int i0_ = ((K0) >> 1) + kw * 8;                                             \
    _Pragma("unroll")                                                           \
    for (int j2_ = 0; j2_ < 8; ++j2_)                                           \
      *(float2*)&PV[2 * j2_] =                                                  \
          *(const float2*)(Bsrc + ((size_t)(bb * 512 + i0_ + j2_) << 13) + 2 * tb); \
  } else if constexpr (GM == 1) {                                               \
    int i0_ = ((K0) >> 1) + kw * 8;                                             \
    _Pragma("unroll")                                                           \
    for (int j2_ = 0; j2_ < 8; ++j2_)                                           \
      *(float2*)&PV[2 * j2_] =                                                  \
          *(const float2*)(Bsrc + ((size_t)(i0_ + j2_) << 15) + bb * 4096 + 2 * tb); \
  } else {                                                                      \
    _Pragma("unroll")                                                           \
    for (int j_ = 0; j_ < 16; ++j_)                                             \
      PV[j_] = Bsrc[(size_t)((K0) + kw * 16 + j_) * N + n0 + nn];               \
  }

  const int sw = (nn >> 1) & 3;
  const int c0 = ((2 * kw) ^ sw) << 3, c1 = ((2 * kw + 1) ^ sw) << 3;

#define STAGE(BUF, PV)                                                          \
  {                                                                             \
    su16x8 pa_[NS], pb_[NS];                                                    \
    _Pragma("unroll")                                                           \
    for (int j_ = 0; j_ < 8; ++j_) {                                            \
      {                                                                         \
        float v_ = PV[j_];                                                      \
        unsigned u_ = __float_as_uint(v_);                                      \
        pa_[0][j_] = (u16)(u_ >> 16);                                           \
        float r_ = v_ - __uint_as_float(u_ & 0xFFFF0000u);                      \
        unsigned ur_ = __float_as_uint(r_);                                     \
        pa_[1][j_] = (u16)(ur_ >> 16);                                          \
        if constexpr (NS == 3) {                                                \
          float r2_ = r_ - __uint_as_float(ur_ & 0xFFFF0000u);                  \
          pa_[2][j_] = (u16)(__float_as_uint(r2_) >> 16);                       \
        }                                                                       \
      }                                                                         \
      {                                                                         \
        float v_ = PV[8 + j_];                                                  \
        unsigned u_ = __float_as_uint(v_);                                      \
        pb_[0][j_] = (u16)(u_ >> 16);                                           \
        float r_ = v_ - __uint_as_float(u_ & 0xFFFF0000u);                      \
        unsigned ur_ = __float_as_uint(r_);                                     \
        pb_[1][j_] = (u16)(ur_ >> 16);                                          \
        if constexpr (NS == 3) {                                                \
          float r2_ = r_ - __uint_as_float(ur_ & 0xFFFF0000u);                  \
          pb_[2][j_] = (u16)(__float_as_uint(r2_) >> 16);                       \
        }                                                                       \
      }                                                                         \
    }                                                                           \
    _Pragma("unroll")                                                           \
    for (int p_ = 0; p_ < NS; ++p_) {                                           \
      *(su16x8*)&Bp[BUF][p_][nn][c0] = pa_[p_];                                 \
      *(su16x8*)&Bp[BUF][p_][nn][c1] = pb_[p_];                                 \
    }                                                                           \
  }

#define COMPUTE(BUF, K0)                                                        \
  {                                                                             \
    bf16x8 bfr_[4][NS];                                                         \
    _Pragma("unroll")                                                           \
    for (int fn_ = 0; fn_ < 4; ++fn_) {                                         \
      int row_ = wc * 64 + fn_ * 16 + li;                                       \
      int cs_ = ((g ^ ((row_ >> 1) & 3)) << 3);                                 \
      _Pragma("unroll")                                                         \
      for (int q_ = 0; q_ < NS; ++q_)                                           \
        bfr_[fn_][q_] = *(const bf16x8*)&Bp[BUF][q_][row_][cs_];                \
    }                                                                           \
    const u16* arow_ = Ap + (size_t)(m0 + wr * 64 + li) * K + (K0) + g * 8;     \
    _Pragma("unroll")                                                           \
    for (int fm_ = 0; fm_ < 4; ++fm_) {                                         \
      bf16x8 afr_[NS];                                                          \
      _Pragma("unroll")                                                         \
      for (int p_ = 0; p_ < NS; ++p_)                                           \
        afr_[p_] = *(const bf16x8*)(arow_ + (size_t)p_ * ASTR + (size_t)fm_ * 16 * K); \
      _Pragma("unroll")                                                         \
      for (int fn_ = 0; fn_ < 4; ++fn_) {                                       \
        f32x4 a_ = acc[fm_][fn_];                                               \
        if constexpr (NS == 3) {                                                \
          a_ = __builtin_amdgcn_mfma_f32_16x16x32_bf16(afr_[2], bfr_[fn_][0], a_, 0, 0, 0); \
          a_ = __builtin_amdgcn_mfma_f32_16x16x32_bf16(afr_[1], bfr_[fn_][1], a_, 0, 0, 0); \
          a_ = __builtin_amdgcn_mfma_f32_16x16x32_bf16(afr_[0], bfr_[fn_][2], a_, 0, 0, 0); \
          a_ = __builtin_amdgcn_mfma_f32_16x16x32_bf16(afr_[1], bfr_[fn_][0], a_, 0, 0, 0); \
          a_ = __builtin_amdgcn_mfma_f32_16x16x32_bf16(afr_[0], bfr_[fn_][1], a_, 0, 0, 0); \
          a_ = __builtin_amdgcn_mfma_f32_16x16x32_bf16(afr_[0], bfr_[fn_][0], a_, 0, 0, 0); \
        } else {                                                                \
          a_ = __builtin_amdgcn_mfma_f32_16x16x32_bf16(afr_[1], bfr_[fn_][0], a_, 0, 0, 0); \
          a_ = __builtin_amdgcn_mfma_f32_16x16x32_bf16(afr_[0], bfr_[fn_][1], a_, 0, 0, 0); \
          a_ = __builtin_amdgcn_mfma_f32_16x16x32_bf16(afr_[0], bfr_[fn_][0], a_, 0, 0, 0); \
        }                                                                       \
        acc[fm_][fn_] = a_;                                                     \
      }                                                                         \
    }                                                                           \
  }

  // prologue: pvA<-t0, pvB<-t1, stage t0, pvA<-t2
  LOADB(pvA, 0)
  LOADB(pvB, 32)
  STAGE(0, pvA)
  if (64 < K) { LOADB(pvA, 64) }
  __syncthreads();

  for (int k0 = 0; k0 < K; k0 += 64) {
    STAGE(1, pvB)                               // tile k0/32 + 1
    if (k0 + 96 < K) { LOADB(pvB, k0 + 96) }    // tile +3
    COMPUTE(0, k0)                              // tile k0/32
    __syncthreads();
    if (k0 + 64 < K) { STAGE(0, pvA) }          // tile +2
    if (k0 + 128 < K) { LOADB(pvA, k0 + 128) }  // tile +4
    COMPUTE(1, k0 + 32)                         // tile +1
    __syncthreads();
  }
#undef LOADB
#undef STAGE
#undef COMPUTE

  // ---- epilogue
  const int mb = m0 + wr * 64 + g * 4;
  const int nb = n0 + wc * 64 + li;
  if constexpr (EPI == 0) {
    #pragma unroll
    for (int fn = 0; fn < 4; ++fn) {
      int n = nb + fn * 16;
      #pragma unroll
      for (int fm = 0; fm < 4; ++fm)
        #pragma unroll
        for (int r = 0; r < 4; ++r) {
          int o = mb + fm * 16 + r;
          Out[(size_t)o * 32768 + n] = acc[fm][fn][r] + bias[o];
        }
    }
  } else if constexpr (EPI == 1) {
    #pragma unroll
    for (int fn = 0; fn < 4; ++fn) {
      int n = nb + fn * 16;
      int b = n >> 11, t = n & 2047;
      #pragma unroll
      for (int fm = 0; fm < 4; ++fm)
        #pragma unroll
        for (int r = 0; r < 4; ++r) {
          int o = mb + fm * 16 + r;
          Out[((size_t)((b << 9) + o)) * 2048 + t] = acc[fm][fn][r] + bias[o];
        }
    }
  } else if constexpr (EPI == 2) {
    #pragma unroll
    for (int fn = 0; fn < 4; ++fn) {
      int n = nb + fn * 16;
      int b = n >> 11, t = n & 2047;
      #pragma unroll
      for (int fm = 0; fm < 4; ++fm)
        #pragma unroll
        for (int rp = 0; rp < 2; ++rp) {
          int m2 = mb + fm * 16 + 2 * rp;
          int o = m2 >> 1;
          float bv = bias[o];
          float2 st = make_float2(acc[fm][fn][2 * rp] + bv, acc[fm][fn][2 * rp + 1] + bv);
          *(float2*)&Out[(size_t)o * 32768 + (size_t)b * 4096 + 2 * t] = st;
        }
    }
  } else {  // EPI == 3
    #pragma unroll
    for (int fn = 0; fn < 4; ++fn) {
      int n = nb + fn * 16;
      int b = n >> 12, t1 = n & 4095;
      #pragma unroll
      for (int fm = 0; fm < 4; ++fm)
        #pragma unroll
        for (int rp = 0; rp < 2; ++rp) {
          int m2 = mb + fm * 16 + 2 * rp;
          int o = m2 >> 1;
          float bv = bias[o];
          float2 st = make_float2(acc[fm][fn][2 * rp] + bv, acc[fm][fn][2 * rp + 1] + bv);
          *(float2*)&Out[((size_t)((b << 9) + o)) * 8192 + 2 * t1] = st;
        }
    }
  }
}

// ---------------- proven fp32 tiled GEMM (e0, zq) ----------------
template <int GATHER, int SCATTER>
__global__ __launch_bounds__(256) void gemm_conv(const float* __restrict__ A,
                                                 const float* __restrict__ Bsrc,
                                                 const float* __restrict__ bias,
                                                 float* __restrict__ Out,
                                                 int M, int K, int N, int Tt) {
  constexpr int BM = 128, BN = 128, BK = 16;
  __shared__ float As[BK][BM + 4];
  __shared__ float Bs[BK][BN + 4];
  int tid = threadIdx.x;
  int tx = tid & 15, ty = tid >> 4;
  int n0 = blockIdx.x * BN, m0 = blockIdx.y * BM;
  int b = n0 / Tt, t0 = n0 % Tt;
  float acc[8][8];
  #pragma unroll
  for (int i = 0; i < 8; i++)
    #pragma unroll
    for (int j = 0; j < 8; j++) acc[i][j] = 0.f;

  for (int k0 = 0; k0 < K; k0 += BK) {
    #pragma unroll
    for (int rep = 0; rep < 2; rep++) {
      int f = tid + rep * 256;
      int row = f >> 2, c4 = (f & 3) << 2;
      int m = m0 + row, k = k0 + c4;
      float4 v = make_float4(0.f, 0.f, 0.f, 0.f);
      if (m < M) {
        if (k + 3 < K) {
          v = *(const float4*)(A + (size_t)m * K + k);
        } else {
          float tmp[4] = {0.f, 0.f, 0.f, 0.f};
          for (int c = 0; c < 4; c++)
            if (k + c < K) tmp[c] = A[(size_t)m * K + k + c];
          v = make_float4(tmp[0], tmp[1], tmp[2], tmp[3]);
        }
      }
      As[c4 + 0][row] = v.x; As[c4 + 1][row] = v.y;
      As[c4 + 2][row] = v.z; As[c4 + 3][row] = v.w;
    }
    #pragma unroll
    for (int rep = 0; rep < 2; rep++) {
      int f = tid + rep * 256;
      int kk = f >> 5, n4 = (f & 31) << 2;
      int k = k0 + kk;
      float4 v = make_float4(0.f, 0.f, 0.f, 0.f);
      if (GATHER == 1) {
        v = *(const float4*)(Bsrc + ((size_t)(b * K + k)) * Tt + t0 + n4);
      } else {
        if (k < K) v = *(const float4*)(Bsrc + (size_t)k * N + n0 + n4);
      }
      *(float4*)&Bs[kk][n4] = v;
    }
    __syncthreads();
    #pragma unroll
    for (int kk = 0; kk < BK; kk++) {
      float a[8], bb[8];
      *(float4*)&a[0] = *(float4*)&As[kk][ty * 8];
      *(float4*)&a[4] = *(float4*)&As[kk][ty * 8 + 4];
      *(float4*)&bb[0] = *(float4*)&Bs[kk][tx * 8];
      *(float4*)&bb[4] = *(float4*)&Bs[kk][tx * 8 + 4];
      #pragma unroll
      for (int i = 0; i < 8; i++)
        #pragma unroll
        for (int j = 0; j < 8; j++) acc[i][j] = fmaf(a[i], bb[j], acc[i][j]);
    }
    __syncthreads();
  }
  if (SCATTER == 0) {
    #pragma unroll
    for (int i = 0; i < 8; i++) {
      int m = m0 + ty * 8 + i;
      if (m < M) {
        float bv = bias ? bias[m] : 0.f;
        float* p = Out + ((size_t)(b * M + m)) * Tt + t0 + tx * 8;
        *(float4*)p = make_float4(acc[i][0] + bv, acc[i][1] + bv, acc[i][2] + bv, acc[i][3] + bv);
        *(float4*)(p + 4) = make_float4(acc[i][4] + bv, acc[i][5] + bv, acc[i][6] + bv, acc[i][7] + bv);
      }
    }
  } else {
    #pragma unroll
    for (int j = 0; j < 8; j++) {
      int n = n0 + tx * 8 + j;
      int m = m0 + ty * 8;
      if (m < M) {
        float* p = Out + (size_t)n * M + m;
        if (m + 7 < M) {
          *(float4*)p = make_float4(acc[0][j], acc[1][j], acc[2][j], acc[3][j]);
          *(float4*)(p + 4) = make_float4(acc[4][j], acc[5][j], acc[6][j], acc[7][j]);
        } else {
          for (int i = 0; i < 8 && m + i < M; i++) p[i] = acc[i][j];
        }
      }
    }
  }
}

// ---------------- RVQ core (proven) ----------------
__global__ __launch_bounds__(256) void rvq_kernel(const float* __restrict__ codebooks,
                                                  const float* __restrict__ e0t,
                                                  const float* __restrict__ cbsW,
                                                  const float* __restrict__ ptW,
                                                  const float* __restrict__ beffW,
                                                  float* __restrict__ Qout,
                                                  float* __restrict__ codesOut,
                                                  float* __restrict__ lossPart) {
  __shared__ float cbv[8][1024];
  __shared__ float cbs2[2][1024];
  __shared__ float Pt[36 * 65];
  __shared__ float est[16][72];
  __shared__ float lred[4];
  int tid = threadIdx.x, wid = tid >> 6, lane = tid & 63;
  int nb0 = blockIdx.x * 16;
  for (int idx = tid; idx < 2340; idx += 256) Pt[idx] = ptW[idx];
  for (int idx = tid; idx < 16 * 72; idx += 256)
    est[idx / 72][idx % 72] = e0t[(size_t)nb0 * 72 + idx] + beffW[idx % 72];
  float lossLocal = 0.f;

  for (int i = 0; i < NQ; i++) {
    __syncthreads();
    const float* cbg = codebooks + (size_t)i * CBS * CBD;
    for (int lin = tid; lin < 2048; lin += 256) {
      int j = lin >> 1, half = (lin & 1) << 2;
      float4 v = *(const float4*)(cbg + (size_t)j * 8 + half);
      cbv[half + 0][j] = v.x; cbv[half + 1][j] = v.y;
      cbv[half + 2][j] = v.z; cbv[half + 3][j] = v.w;
    }
    for (int lin = tid; lin < 1024; lin += 256) {
      cbs2[0][lin] = cbsW[((size_t)i * 2 + 0) * 1024 + lin];
      cbs2[1][lin] = cbsW[((size_t)i * 2 + 1) * 1024 + lin];
    }
    __syncthreads();

    float ze[4][8], en[4][8];
    #pragma unroll
    for (int w = 0; w < 4; w++) {
      int tokl = wid * 4 + w;
      float ss = 0.f;
      #pragma unroll
      for (int d = 0; d < 8; d++) { float v = est[tokl][i * 8 + d]; ze[w][d] = v; ss += v * v; }
      float inv = 1.0f / fmaxf(sqrtf(ss), EPSN);
      #pragma unroll
      for (int d = 0; d < 8; d++) en[w][d] = ze[w][d] * inv;
    }
    float best[4]; int bidx[4];
    #pragma unroll
    for (int w = 0; w < 4; w++) { best[w] = -INFINITY; bidx[w] = 0; }
    #pragma unroll 4
    for (int r = 0; r < 16; r++) {
      int j = lane + (r << 6);
      float c0 = cbv[0][j], c1 = cbv[1][j], c2 = cbv[2][j], c3 = cbv[3][j];
      float c4 = cbv[4][j], c5 = cbv[5][j], c6 = cbv[6][j], c7 = cbv[7][j];
      float ti = cbs2[0][j], ns = cbs2[1][j];
      #pragma unroll
      for (int w = 0; w < 4; w++) {
        float dt = en[w][0] * c0;
        dt = fmaf(en[w][1], c1, dt); dt = fmaf(en[w][2], c2, dt);
        dt = fmaf(en[w][3], c3, dt); dt = fmaf(en[w][4], c4, dt);
        dt = fmaf(en[w][5], c5, dt); dt = fmaf(en[w][6], c6, dt);
        dt = fmaf(en[w][7], c7, dt);
        float s = fmaf(dt, ti, -ns);
        if (s > best[w]) { best[w] = s; bidx[w] = j; }
      }
    }
    #pragma unroll
    for (int w = 0; w < 4; w++) {
      #pragma unroll
      for (int off = 32; off; off >>= 1) {
        float so = __shfl_xor(best[w], off);
        int jo = __shfl_xor(bidx[w], off);
        if (so > best[w] || (so == best[w] && jo < bidx[w])) { best[w] = so; bidx[w] = jo; }
      }
    }
    int d = lane & 7;
    #pragma unroll
    for (int w = 0; w < 4; w++) {
      int jstar = bidx[w];
      int tokl = wid * 4 + w;
      int n = nb0 + tokl;
      float qd = cbv[d][jstar];
      float diff = ze[w][d] - qd;
      float sq = diff * diff;
      sq += __shfl_xor(sq, 1); sq += __shfl_xor(sq, 2); sq += __shfl_xor(sq, 4);
      if (lane == 0) lossLocal += sq;
      if (lane < 8) Qout[(size_t)(i * 8 + lane) * NTOK + n] = qd;
      if (lane == 0) codesOut[(size_t)((n >> 11) * NQ + i) * TQ + (n & (TQ - 1))] = (float)jstar;
      if (i < NQ - 1) {
        int f = lane >> 3, d2 = lane & 7;
        int ip = i + 1 + f;
        if (ip < NQ) {
          int tri = (ip * (ip - 1)) / 2 + i;
          const float* prow = &Pt[tri * 65 + d2 * 8];
          float s = 0.f;
          #pragma unroll
          for (int dp = 0; dp < 8; dp++) s = fmaf(prow[dp], cbv[dp][jstar], s);
          est[tokl][ip * 8 + d2] -= s;
        }
      }
    }
  }
  if (lane == 0) lred[wid] = lossLocal;
  __syncthreads();
  if (tid == 0) {
    float s = ((lred[0] + lred[1]) + lred[2]) + lred[3];
    lossPart[blockIdx.x] = s;
  }
}

__global__ void loss_fin(const float* __restrict__ lossPart, float* __restrict__ out) {
  __shared__ float s[256];
  int tid = threadIdx.x;
  float v = 0.f;
  for (int r = 0; r < 4; r++) v += lossPart[tid + r * 256];
  s[tid] = v;
  __syncthreads();
  for (int w = 128; w; w >>= 1) {
    if (tid < w) s[tid] += s[tid + w];
    __syncthreads();
  }
  if (tid == 0) {
    float total = s[0] / 131072.0f;
    out[0] = total;
    out[1] = total;
  }
}

// ---------------- launch ----------------
extern "C" void kernel_launch(void* const* d_in, const int* in_sizes, int n_in,
                              void* d_out, int out_size, void* d_ws, size_t ws_size,
                              hipStream_t stream) {
  const float* z      = (const float*)d_in[0];
  const float* down_w = (const float*)d_in[1];
  const float* down_b = (const float*)d_in[2];
  const float* up_w   = (const float*)d_in[3];
  const float* up_b   = (const float*)d_in[4];
  const float* in_v   = (const float*)d_in[5];
  const float* in_g   = (const float*)d_in[6];
  const float* in_b   = (const float*)d_in[7];
  const float* out_v  = (const float*)d_in[8];
  const float* out_g  = (const float*)d_in[9];
  const float* out_b  = (const float*)d_in[10];
  const float* codebooks = (const float*)d_in[11];
  float* ws = (float*)d_ws;
  float* xout = (float*)d_out;
  float* codesOut = xout + (size_t)8 * 512 * 8192;
  float* lossOut = codesOut + (size_t)8 * NQ * TQ;
  const u16* dwp = (const u16*)(ws + OFF_DWP);
  const u16* uwp = (const u16*)(ws + OFF_UWP);

  hipLaunchKernelGGL(prep_wp, dim3(8192), dim3(256), 0, stream, down_w, up_w, ws);
  hipLaunchKernelGGL(prep_small1, dim3(74), dim3(256), 0, stream,
                     in_v, in_g, out_v, out_g, out_b, codebooks, ws);
  hipLaunchKernelGGL(prep2, dim3(594), dim3(256), 0, stream, in_b, out_b, ws);
  // down1: A=dwp[l=0], B=z paired gather -> x1 [512][32768]
  hipLaunchKernelGGL((gemmT<3, 0, 0>), dim3(256, 4), dim3(256), 0, stream,
                     dwp, z, down_b, ws + OFF_X1, 1024, 32768);
  // down2: A=dwp[l=1], B=x1 paired gather -> x2 [8][512][2048]
  hipLaunchKernelGGL((gemmT<3, 1, 1>), dim3(128, 4), dim3(256), 0, stream,
                     dwp + (size_t)3 * ASTR, ws + OFF_X1, down_b + 512, ws + OFF_X2, 1024, 16384);
  // e0 (fp32): WinN[72,512] @ x2 -> e0t [16384][72]
  hipLaunchKernelGGL((gemm_conv<1, 1>), dim3(128, 1), dim3(256), 0, stream,
                     ws + OFF_WINN, ws + OFF_X2, (const float*)nullptr, ws + OFF_E0T, 72, 512, 16384, 2048);
  // RVQ
  hipLaunchKernelGGL(rvq_kernel, dim3(1024), dim3(256), 0, stream,
                     codebooks, ws + OFF_E0T, ws + OFF_CBS, ws + OFF_PT, ws + OFF_BEFF,
                     ws + OFF_Q, codesOut, ws + OFF_LOSS);
  // zq (fp32, K=72): WoutS @ Q + bsum -> zqf [512][16384]
  hipLaunchKernelGGL((gemm_conv<2, 0>), dim3(128, 4), dim3(256), 0, stream,
                     ws + OFF_WOUT, ws + OFF_Q, ws + OFF_BSUM, ws + OFF_ZQF, 512, 72, 16384, 16384);
  // up1: A=uwp[l=0], B=zqf rows -> U2 [512][32768]
  hipLaunchKernelGGL((gemmT<2, 2, 2>), dim3(128, 8), dim3(256), 0, stream,
                     uwp, ws + OFF_ZQF, up_b, ws + OFF_U2, 512, 16384);
  // up2: A=uwp[l=1], B=U2 rows -> x fp32 to d_out
  hipLaunchKernelGGL((gemmT<2, 2, 3>), dim3(256, 8), dim3(256), 0, stream,
                     uwp + (size_t)2 * ASTR, ws + OFF_U2, up_b + 512, xout, 512, 32768);
  hipLaunchKernelGGL(loss_fin, dim3(1), dim3(256), 0, stream, ws + OFF_LOSS, lossOut);
}

// Round 12
// 860.660 us; speedup vs baseline: 1.8591x; 1.1223x over previous
//
#include <hip/hip_runtime.h>
#include <math.h>

// FireflyVQ R12: algebraic fusion.
// Down: Conv∘Conv = Conv(k4s4): x2 = W_d[512][2048]·zg + b_d (3-split MFMA).
// Up:   x = Wx[2048][72]·Q + bx (fp32, memory-bound) -- zq/up1/up2 collapsed.
// W_d / W_eff / Wx computed on-device per launch (small strided matmuls).
// e0 (fp32 gemm_conv) and RVQ unchanged.

using u16 = unsigned short;
typedef __attribute__((ext_vector_type(8))) short bf16x8;
typedef __attribute__((ext_vector_type(8))) u16 su16x8;
typedef __attribute__((ext_vector_type(4))) float f32x4;

constexpr int NQ = 9, CBS = 1024, CBD = 8;
constexpr int TQ = 2048;
constexpr int NTOK = 16384;
constexpr int APS = 1048576;   // u16 per W_d split plane (512*2048)
#define EPSN 1e-12f

// ---- ws layout (float offsets), ~58.7 MB
constexpr size_t OFF_X2    = 0;                  // [8][512][2048] fp32
constexpr size_t OFF_E0T   = 8388608;            // [16384][72]
constexpr size_t OFF_Q     = 9568256;            // [72][16384]
constexpr size_t OFF_WD    = 10747904;           // W_d [512][2048] fp32
constexpr size_t OFF_WDP   = 11796480;           // 3 u16 planes of W_d (1,572,864 fl)
constexpr size_t OFF_WEFF  = 13369344;           // W_eff [2048][512] fp32
constexpr size_t OFF_WX    = 14417920;           // Wx [2048][80] fp32 (col72 = W_eff·bsum)
constexpr size_t OFF_WINN  = 14581760;           // [72][512]
constexpr size_t OFF_WOUTS = 14618624;           // WoutS2 [512][80] (col72=bsum, 73..79=0)
constexpr size_t OFF_CBS   = 14659584;           // [9][2][1024]
constexpr size_t OFF_PT    = 14678016;           // 2340
constexpr size_t OFF_BEFF  = 14680356;           // 72
constexpr size_t OFF_BSUM  = 14680428;           // 512
constexpr size_t OFF_BD    = 14680940;           // 512
constexpr size_t OFF_BUP   = 14681452;           // [512][2]
constexpr size_t OFF_LOSS  = 14682476;           // 1024

// ---------------- prep_small1: WinN, WoutS2, cbScal, bsum, b_d, bup ----------------
__global__ void prep_small1(const float* __restrict__ in_v, const float* __restrict__ in_g,
                            const float* __restrict__ out_v, const float* __restrict__ out_g,
                            const float* __restrict__ out_b, const float* __restrict__ codebooks,
                            const float* __restrict__ down_w, const float* __restrict__ down_b,
                            const float* __restrict__ up_w, const float* __restrict__ up_b,
                            float* __restrict__ ws) {
  int bid = blockIdx.x, tid = threadIdx.x;
  int wid4 = tid >> 6, lane = tid & 63;
  if (bid < 18) {  // WinN rows
    int wid = bid * 4 + wid4;
    if (wid < 72) {
      const float* v = in_v + (size_t)wid * 512;
      float ss = 0.f;
      for (int c = lane; c < 512; c += 64) ss += v[c] * v[c];
      #pragma unroll
      for (int o = 32; o; o >>= 1) ss += __shfl_xor(ss, o);
      float sc = in_g[wid] / sqrtf(ss);
      float* dst = ws + OFF_WINN + (size_t)wid * 512;
      for (int c = lane; c < 512; c += 64) dst[c] = v[c] * sc;
    }
  } else if (bid < 36) {  // WoutS2 [c][80], cols 0..71
    int r = (bid - 18) * 256 + tid;
    if (r < 4608) {
      int i = r >> 9, c = r & 511;
      const float* v = out_v + (size_t)r * 8;
      float ss = 0.f;
      #pragma unroll
      for (int d = 0; d < 8; d++) ss += v[d] * v[d];
      float sc = out_g[r] / sqrtf(ss);
      float* dst = ws + OFF_WOUTS + (size_t)c * 80 + i * 8;
      #pragma unroll
      for (int d = 0; d < 8; d++) dst[d] = v[d] * sc;
    }
  } else if (bid < 72) {  // codebook scalars
    int r = (bid - 36) * 256 + tid;
    if (r < 9216) {
      int i = r >> 10, j = r & 1023;
      const float* v = codebooks + (size_t)r * 8;
      float ss = 0.f;
      #pragma unroll
      for (int d = 0; d < 8; d++) ss += v[d] * v[d];
      float nm = fmaxf(sqrtf(ss), EPSN);
      float nsq = 0.f;
      #pragma unroll
      for (int d = 0; d < 8; d++) { float cn = v[d] / nm; nsq += cn * cn; }
      ws[OFF_CBS + ((size_t)i * 2 + 0) * 1024 + j] = 2.0f / nm;
      ws[OFF_CBS + ((size_t)i * 2 + 1) * 1024 + j] = nsq;
    }
  } else if (bid < 74) {  // bsum + WoutS2 col 72..79
    int c = (bid - 72) * 256 + tid;
    if (c < 512) {
      float s = 0.f;
      #pragma unroll
      for (int j = 0; j < 9; j++) s += out_b[j * 512 + c];
      ws[OFF_BSUM + c] = s;
      ws[OFF_WOUTS + (size_t)c * 80 + 72] = s;
      #pragma unroll
      for (int d = 73; d < 80; d++) ws[OFF_WOUTS + (size_t)c * 80 + d] = 0.f;
    }
  } else if (bid < 202) {  // b_d[o], one wave each
    int o = (bid - 74) * 4 + wid4;
    float s = 0.f;
    for (int m = lane; m < 512; m += 64) {
      float w0 = down_w[524288 + (size_t)o * 1024 + m * 2];
      float w1 = down_w[524288 + (size_t)o * 1024 + m * 2 + 1];
      s += (w0 + w1) * down_b[m];
    }
    #pragma unroll
    for (int off = 32; off; off >>= 1) s += __shfl_xor(s, off);
    if (lane == 0) ws[OFF_BD + o] = s + down_b[512 + o];
  } else {  // bid 202..457: bup[c][j2], one wave each (1024)
    int gw = (bid - 202) * 4 + wid4;
    int c = gw >> 1, j2 = gw & 1;
    float s = 0.f;
    for (int m = lane; m < 512; m += 64)
      s += up_w[524288 + (size_t)m * 1024 + c * 2 + j2] * up_b[m];
    #pragma unroll
    for (int off = 32; off; off >>= 1) s += __shfl_xor(s, off);
    if (lane == 0) ws[OFF_BUP + gw] = s + up_b[512 + c];
  }
}

// ---------------- prep2: P matrix + beff (WoutS stride 80) ----------------
__global__ void prep2(const float* __restrict__ in_b, const float* __restrict__ out_b,
                      float* __restrict__ ws) {
  int gw = blockIdx.x * 4 + (threadIdx.x >> 6), lane = threadIdx.x & 63;
  const float* WinN = ws + OFF_WINN;
  const float* WoutS = ws + OFF_WOUTS;
  if (gw < 2304) {
    int tri = gw >> 6, dd = gw & 63;
    int ip = 1;
    while (tri >= ip * (ip + 1) / 2) ip++;
    int i = tri - ip * (ip - 1) / 2;
    int d = dd >> 3, dp = dd & 7;
    const float* a = WinN + (size_t)(ip * 8 + d) * 512;
    float s = 0.f;
    for (int c = lane; c < 512; c += 64) s += a[c] * WoutS[(size_t)c * 80 + i * 8 + dp];
    #pragma unroll
    for (int o = 32; o; o >>= 1) s += __shfl_xor(s, o);
    if (lane == 0) ws[OFF_PT + (size_t)tri * 65 + dd] = s;
  } else if (gw < 2376) {
    int r = gw - 2304;
    int i = r >> 3;
    const float* a = WinN + (size_t)r * 512;
    float s = 0.f;
    for (int c = lane; c < 512; c += 64) {
      float ob = 0.f;
      for (int j = 0; j < i; j++) ob += out_b[j * 512 + c];
      s += a[c] * ob;
    }
    #pragma unroll
    for (int o = 32; o; o >>= 1) s += __shfl_xor(s, o);
    if (lane == 0) ws[OFF_BEFF + r] = in_b[r] - s;
  }
}

// ---------------- smallmm: 512x512x512 strided matmuls for W_d / W_eff ----------------
// WHICH 0 (W_d):  OUT[o*2048 + c*4 + j] = sum_m dw2[o][m][j>>1] * dw1[m][c][j&1]
//   A(a,m) = src[524288 + a*1024 + m*2 + (j>>1)], B(m,b) = src[m*1024 + b*2 + (j&1)]
// WHICH 1 (Weff): OUT[(c*4+j)*512 + i] = sum_m up1w[i][m][j>>1] * up2w[m][c][j&1]
//   A(a=c,m) = src[524288 + m*1024 + a*2 + (j&1)], B(m,b=i) = src[b*1024 + m*2 + (j>>1)]
template <int WHICH>
__global__ __launch_bounds__(256) void smallmm(const float* __restrict__ src,
                                               float* __restrict__ outp) {
  __shared__ float As[32][68];
  __shared__ float Bs[32][68];
  const int tid = threadIdx.x;
  const int tx = tid & 15, ty = tid >> 4;
  const int b0 = blockIdx.x * 64, a0 = blockIdx.y * 64, j = blockIdx.z;
  const int jh = j >> 1, jl = j & 1;
  float acc[4][4];
  #pragma unroll
  for (int i = 0; i < 4; i++)
    #pragma unroll
    for (int k = 0; k < 4; k++) acc[i][k] = 0.f;

  for (int k0 = 0; k0 < 512; k0 += 32) {
    #pragma unroll
    for (int rep = 0; rep < 8; rep++) {
      int f = tid + rep * 256;
      int aa = f >> 5, mm = f & 31;
      size_t ai;
      if constexpr (WHICH == 0) ai = 524288 + (size_t)(a0 + aa) * 1024 + (k0 + mm) * 2 + jh;
      else                      ai = 524288 + (size_t)(k0 + mm) * 1024 + (a0 + aa) * 2 + jl;
      As[mm][aa] = src[ai];
      int mm2 = f >> 6, bb = f & 63;
      size_t bi;
      if constexpr (WHICH == 0) bi = (size_t)(k0 + mm2) * 1024 + (b0 + bb) * 2 + jl;
      else                      bi = (size_t)(b0 + bb) * 1024 + (k0 + mm2) * 2 + jh;
      Bs[mm2][bb] = src[bi];
    }
    __syncthreads();
    #pragma unroll
    for (int kk = 0; kk < 32; kk++) {
      float av[4], bv[4];
      #pragma unroll
      for (int i = 0; i < 4; i++) av[i] = As[kk][ty * 4 + i];
      #pragma unroll
      for (int i = 0; i < 4; i++) bv[i] = Bs[kk][tx * 4 + i];
      #pragma unroll
      for (int i = 0; i < 4; i++)
        #pragma unroll
        for (int k = 0; k < 4; k++) acc[i][k] = fmaf(av[i], bv[k], acc[i][k]);
    }
    __syncthreads();
  }
  #pragma unroll
  for (int i = 0; i < 4; i++) {
    int a = a0 + ty * 4 + i;
    #pragma unroll
    for (int k = 0; k < 4; k++) {
      int b = b0 + tx * 4 + k;
      if constexpr (WHICH == 0) outp[(size_t)a * 2048 + b * 4 + j] = acc[i][k];
      else                      outp[((size_t)a * 4 + j) * 512 + b] = acc[i][k];
    }
  }
}

// ---------------- split W_d into 3 bf16 truncation planes ----------------
__global__ void prep_wdsplit(const float* __restrict__ wd, u16* __restrict__ wdp) {
  int idx = blockIdx.x * 256 + threadIdx.x;
  float v = wd[idx];
  unsigned u = __float_as_uint(v);
  wdp[idx] = (u16)(u >> 16);
  float r = v - __uint_as_float(u & 0xFFFF0000u);
  unsigned ur = __float_as_uint(r);
  wdp[APS + idx] = (u16)(ur >> 16);
  float r2 = r - __uint_as_float(ur & 0xFFFF0000u);
  wdp[2 * APS + idx] = (u16)(__float_as_uint(r2) >> 16);
}

// ---------------- prep_wx: Wx[2048][80] = W_eff @ WoutS2 ----------------
__global__ __launch_bounds__(256) void prep_wx(const float* __restrict__ weff,
                                               const float* __restrict__ wouts,
                                               float* __restrict__ wx) {
  __shared__ float Wes[16][512];
  __shared__ float WSs[64][80];
  const int tid = threadIdx.x;
  const int m0 = blockIdx.x * 16;
  #pragma unroll
  for (int rep = 0; rep < 32; rep++) {
    int f = tid + rep * 256;
    Wes[f >> 9][f & 511] = weff[(size_t)(m0 + (f >> 9)) * 512 + (f & 511)];
  }
  const int rowq = tid >> 4, rq = tid & 15;
  float accs[5] = {0.f, 0.f, 0.f, 0.f, 0.f};
  for (int k0 = 0; k0 < 512; k0 += 64) {
    __syncthreads();
    #pragma unroll
    for (int rep = 0; rep < 20; rep++) {
      int f = tid + rep * 256;
      int kk = f / 80, col = f % 80;
      WSs[kk][col] = wouts[(size_t)(k0 + kk) * 80 + col];
    }
    __syncthreads();
    #pragma unroll 4
    for (int kk = 0; kk < 64; kk++) {
      float we = Wes[rowq][k0 + kk];
      #pragma unroll
      for (int s = 0; s < 5; s++) accs[s] = fmaf(we, WSs[kk][rq + 16 * s], accs[s]);
    }
  }
  #pragma unroll
  for (int s = 0; s < 5; s++) {
    int r = rq + 16 * s;
    if (r < 73) wx[(size_t)(m0 + rowq) * 80 + r] = accs[s];
  }
  if (tid < 112) {
    int row = tid / 7, col = 73 + tid % 7;
    wx[(size_t)(m0 + row) * 80 + col] = 0.f;
  }
}

// ---------------- fused down GEMM: x2 = W_d 3-split MFMA @ zg + b_d ----------------
// M=512, K=2048 (k = c*4+j), N=16384. R11 v4 structure: dbuf LDS, swizzle, 2-deep prefetch.
__global__ __launch_bounds__(256) void gemm_down(const u16* __restrict__ Ap,
                                                 const float* __restrict__ z,
                                                 const float* __restrict__ bias,
                                                 float* __restrict__ Out) {
  constexpr int NS = 3, K = 2048;
  __shared__ u16 Bp[2][NS][128][32];
  const int tid = threadIdx.x;
  const int w = tid >> 6, l = tid & 63;
  const int g = l >> 4, li = l & 15;
  const int wr = w >> 1, wc = w & 1;
  const int n0 = blockIdx.x * 128, m0 = blockIdx.y * 128;
  const int nn = tid & 127, kw = tid >> 7;
  const int bb = n0 >> 11;
  const int tb = (n0 & 2047) + nn;

  f32x4 acc[4][4];
  #pragma unroll
  for (int a = 0; a < 4; a++)
    #pragma unroll
    for (int b = 0; b < 4; b++) acc[a][b] = (f32x4){0.f, 0.f, 0.f, 0.f};

  float pvA[16], pvB[16];

#define LOADB(PV, K0)                                                           \
  {                                                                             \
    int c0_ = ((K0) >> 2) + kw * 4;                                             \
    _Pragma("unroll")                                                           \
    for (int cc_ = 0; cc_ < 4; ++cc_)                                           \
      *(float4*)&PV[4 * cc_] =                                                  \
          *(const float4*)(z + ((size_t)(bb * 512 + c0_ + cc_) << 13) + 4 * tb);\
  }

  const int sw = (nn >> 1) & 3;
  const int c0 = ((2 * kw) ^ sw) << 3, c1 = ((2 * kw + 1) ^ sw) << 3;

#define STAGE(BUF, PV)                                                          \
  {                                                                             \
    su16x8 pa_[NS], pb_[NS];                                                    \
    _Pragma("unroll")                                                           \
    for (int j_ = 0; j_ < 8; ++j_) {                                            \
      {                                                                         \
        float v_ = PV[j_];                                                      \
        unsigned u_ = __float_as_uint(v_);                                      \
        pa_[0][j_] = (u16)(u_ >> 16);                                           \
        float r_ = v_ - __uint_as_float(u_ & 0xFFFF0000u);                      \
        unsigned ur_ = __float_as_uint(r_);                                     \
        pa_[1][j_] = (u16)(ur_ >> 16);                                          \
        float r2_ = r_ - __uint_as_float(ur_ & 0xFFFF0000u);                    \
        pa_[2][j_] = (u16)(__float_as_uint(r2_) >> 16);                         \
      }                                                                         \
      {                                                                         \
        float v_ = PV[8 + j_];                                                  \
        unsigned u_ = __float_as_uint(v_);                                      \
        pb_[0][j_] = (u16)(u_ >> 16);                                           \
        float r_ = v_ - __uint_as_float(u_ & 0xFFFF0000u);                      \
        unsigned ur_ = __float_as_uint(r_);                                     \
        pb_[1][j_] = (u16)(ur_ >> 16);                                          \
        float r2_ = r_ - __uint_as_float(ur_ & 0xFFFF0000u);                    \
        pb_[2][j_] = (u16)(__float_as_uint(r2_) >> 16);                         \
      }                                                                         \
    }                                                                           \
    _Pragma("unroll")                                                           \
    for (int p_ = 0; p_ < NS; ++p_) {                                           \
      *(su16x8*)&Bp[BUF][p_][nn][c0] = pa_[p_];                                 \
      *(su16x8*)&Bp[BUF][p_][nn][c1] = pb_[p_];                                 \
    }                                                                           \
  }

#define COMPUTE(BUF, K0)                                                        \
  {                                                                             \
    bf16x8 bfr_[4][NS];                                                         \
    _Pragma("unroll")                                                           \
    for (int fn_ = 0; fn_ < 4; ++fn_) {                                         \
      int row_ = wc * 64 + fn_ * 16 + li;                                       \
      int cs_ = ((g ^ ((row_ >> 1) & 3)) << 3);                                 \
      _Pragma("unroll")                                                         \
      for (int q_ = 0; q_ < NS; ++q_)                                           \
        bfr_[fn_][q_] = *(const bf16x8*)&Bp[BUF][q_][row_][cs_];                \
    }                                                                           \
    const u16* arow_ = Ap + (size_t)(m0 + wr * 64 + li) * K + (K0) + g * 8;     \
    _Pragma("unroll")                                                           \
    for (int fm_ = 0; fm_ < 4; ++fm_) {                                         \
      bf16x8 afr_[NS];                                                          \
      _Pragma("unroll")                                                         \
      for (int p_ = 0; p_ < NS; ++p_)                                           \
        afr_[p_] = *(const bf16x8*)(arow_ + (size_t)p_ * APS + (size_t)fm_ * 16 * K); \
      _Pragma("unroll")                                                         \
      for (int fn_ = 0; fn_ < 4; ++fn_) {                                       \
        f32x4 a_ = acc[fm_][fn_];                                               \
        a_ = __builtin_amdgcn_mfma_f32_16x16x32_bf16(afr_[2], bfr_[fn_][0], a_, 0, 0, 0); \
        a_ = __builtin_amdgcn_mfma_f32_16x16x32_bf16(afr_[1], bfr_[fn_][1], a_, 0, 0, 0); \
        a_ = __builtin_amdgcn_mfma_f32_16x16x32_bf16(afr_[0], bfr_[fn_][2], a_, 0, 0, 0); \
        a_ = __builtin_amdgcn_mfma_f32_16x16x32_bf16(afr_[1], bfr_[fn_][0], a_, 0, 0, 0); \
        a_ = __builtin_amdgcn_mfma_f32_16x16x32_bf16(afr_[0], bfr_[fn_][1], a_, 0, 0, 0); \
        a_ = __builtin_amdgcn_mfma_f32_16x16x32_bf16(afr_[0], bfr_[fn_][0], a_, 0, 0, 0); \
      acc[fm_][fn_] = a_;                                                       \
      }                                                                         \
    }                                                                           \
  }

  LOADB(pvA, 0)
  LOADB(pvB, 32)
  STAGE(0, pvA)
  LOADB(pvA, 64)
  __syncthreads();

  for (int k0 = 0; k0 < K; k0 += 64) {
    STAGE(1, pvB)
    if (k0 + 96 < K) { LOADB(pvB, k0 + 96) }
    COMPUTE(0, k0)
    __syncthreads();
    if (k0 + 64 < K) { STAGE(0, pvA) }
    if (k0 + 128 < K) { LOADB(pvA, k0 + 128) }
    COMPUTE(1, k0 + 32)
    __syncthreads();
  }
#undef LOADB
#undef STAGE
#undef COMPUTE

  const int mb = m0 + wr * 64 + g * 4;
  const int nb = n0 + wc * 64 + li;
  #pragma unroll
  for (int fn = 0; fn < 4; ++fn) {
    int n = nb + fn * 16;
    int b = n >> 11, t = n & 2047;
    #pragma unroll
    for (int fm = 0; fm < 4; ++fm)
      #pragma unroll
      for (int r = 0; r < 4; ++r) {
        int o = mb + fm * 16 + r;
        Out[((size_t)((b << 9) + o)) * 2048 + t] = acc[fm][fn][r] + bias[o];
      }
  }
}

// ---------------- proven fp32 tiled GEMM (e0 only) ----------------
template <int GATHER, int SCATTER>
__global__ __launch_bounds__(256) void gemm_conv(const float* __restrict__ A,
                                                 const float* __restrict__ Bsrc,
                                                 const float* __restrict__ bias,
                                                 float* __restrict__ Out,
                                                 int M, int K, int N, int Tt) {
  constexpr int BM = 128, BN = 128, BK = 16;
  __shared__ float As[BK][BM + 4];
  __shared__ float Bs[BK][BN + 4];
  int tid = threadIdx.x;
  int tx = tid & 15, ty = tid >> 4;
  int n0 = blockIdx.x * BN, m0 = blockIdx.y * BM;
  int b = n0 / Tt, t0 = n0 % Tt;
  float acc[8][8];
  #pragma unroll
  for (int i = 0; i < 8; i++)
    #pragma unroll
    for (int j = 0; j < 8; j++) acc[i][j] = 0.f;

  for (int k0 = 0; k0 < K; k0 += BK) {
    #pragma unroll
    for (int rep = 0; rep < 2; rep++) {
      int f = tid + rep * 256;
      int row = f >> 2, c4 = (f & 3) << 2;
      int m = m0 + row, k = k0 + c4;
      float4 v = make_float4(0.f, 0.f, 0.f, 0.f);
      if (m < M) {
        if (k + 3 < K) {
          v = *(const float4*)(A + (size_t)m * K + k);
        } else {
          float tmp[4] = {0.f, 0.f, 0.f, 0.f};
          for (int c = 0; c < 4; c++)
            if (k + c < K) tmp[c] = A[(size_t)m * K + k + c];
          v = make_float4(tmp[0], tmp[1], tmp[2], tmp[3]);
        }
      }
      As[c4 + 0][row] = v.x; As[c4 + 1][row] = v.y;
      As[c4 + 2][row] = v.z; As[c4 + 3][row] = v.w;
    }
    #pragma unroll
    for (int rep = 0; rep < 2; rep++) {
      int f = tid + rep * 256;
      int kk = f >> 5, n4 = (f & 31) << 2;
      int k = k0 + kk;
      float4 v = make_float4(0.f, 0.f, 0.f, 0.f);
      if (GATHER == 1) {
        v = *(const float4*)(Bsrc + ((size_t)(b * K + k)) * Tt + t0 + n4);
      } else {
        if (k < K) v = *(const float4*)(Bsrc + (size_t)k * N + n0 + n4);
      }
      *(float4*)&Bs[kk][n4] = v;
    }
    __syncthreads();
    #pragma unroll
    for (int kk = 0; kk < BK; kk++) {
      float a[8], bb[8];
      *(float4*)&a[0] = *(float4*)&As[kk][ty * 8];
      *(float4*)&a[4] = *(float4*)&As[kk][ty * 8 + 4];
      *(float4*)&bb[0] = *(float4*)&Bs[kk][tx * 8];
      *(float4*)&bb[4] = *(float4*)&Bs[kk][tx * 8 + 4];
      #pragma unroll
      for (int i = 0; i < 8; i++)
        #pragma unroll
        for (int j = 0; j < 8; j++) acc[i][j] = fmaf(a[i], bb[j], acc[i][j]);
    }
    __syncthreads();
  }
  if (SCATTER == 0) {
    #pragma unroll
    for (int i = 0; i < 8; i++) {
      int m = m0 + ty * 8 + i;
      if (m < M) {
        float bv = bias ? bias[m] : 0.f;
        float* p = Out + ((size_t)(b * M + m)) * Tt + t0 + tx * 8;
        *(float4*)p = make_float4(acc[i][0] + bv, acc[i][1] + bv, acc[i][2] + bv, acc[i][3] + bv);
        *(float4*)(p + 4) = make_float4(acc[i][4] + bv, acc[i][5] + bv, acc[i][6] + bv, acc[i][7] + bv);
      }
    }
  } else {
    #pragma unroll
    for (int j = 0; j < 8; j++) {
      int n = n0 + tx * 8 + j;
      int m = m0 + ty * 8;
      if (m < M) {
        float* p = Out + (size_t)n * M + m;
        if (m + 7 < M) {
          *(float4*)p = make_float4(acc[0][j], acc[1][j], acc[2][j], acc[3][j]);
          *(float4*)(p + 4) = make_float4(acc[4][j], acc[5][j], acc[6][j], acc[7][j]);
        } else {
          for (int i = 0; i < 8 && m + i < M; i++) p[i] = acc[i][j];
        }
      }
    }
  }
}

// ---------------- xfin: x = Wx[2048][72] @ Q + bx ----------------
// Block: 128 m' x 128 n, no K-loop. m' = c*4+j -> float4 stores over j.
__global__ __launch_bounds__(256) void xfin(const float* __restrict__ wx,
                                            const float* __restrict__ Q,
                                            const float* __restrict__ bup,
                                            float* __restrict__ xout) {
  __shared__ float Wxs[128][80];
  __shared__ float Qs[128][80];
  const int tid = threadIdx.x;
  const int n0 = blockIdx.x * 128, m0 = blockIdx.y * 128;
  // stage Wx rows (contiguous copy)
  #pragma unroll
  for (int rep = 0; rep < 10; rep++) {
    int f = tid + rep * 256;
    *(float4*)&Wxs[0][f * 4] = *(const float4*)(wx + (size_t)m0 * 80 + f * 4);
  }
  // stage Q transposed: Qs[n][r]
  {
    int nn = tid & 127, r0 = tid >> 7;
    for (int r = r0; r < 72; r += 2)
      Qs[nn][r] = Q[(size_t)r * 16384 + n0 + nn];
  }
  __syncthreads();

  const int txn = tid & 15, tym = tid >> 4;
  float acc[8][8];
  #pragma unroll
  for (int i = 0; i < 8; i++)
    #pragma unroll
    for (int j = 0; j < 8; j++) acc[i][j] = 0.f;

  #pragma unroll 2
  for (int r4 = 0; r4 < 18; r4++) {
    float4 wv[8], qv[8];
    #pragma unroll
    for (int i = 0; i < 8; i++) wv[i] = *(const float4*)&Wxs[tym * 8 + i][r4 * 4];
    #pragma unroll
    for (int j = 0; j < 8; j++) qv[j] = *(const float4*)&Qs[txn * 8 + j][r4 * 4];
    #pragma unroll
    for (int i = 0; i < 8; i++)
      #pragma unroll
      for (int j = 0; j < 8; j++) {
        acc[i][j] = fmaf(wv[i].x, qv[j].x, acc[i][j]);
        acc[i][j] = fmaf(wv[i].y, qv[j].y, acc[i][j]);
        acc[i][j] = fmaf(wv[i].z, qv[j].z, acc[i][j]);
        acc[i][j] = fmaf(wv[i].w, qv[j].w, acc[i][j]);
      }
  }

  float bxv[8];
  #pragma unroll
  for (int mi = 0; mi < 8; mi++) {
    int mp = m0 + tym * 8 + mi;
    bxv[mi] = Wxs[tym * 8 + mi][72] + bup[(mp >> 2) * 2 + (mp & 1)];
  }
  #pragma unroll
  for (int cg = 0; cg < 2; cg++) {
    int mp0 = m0 + tym * 8 + cg * 4;
    int c = mp0 >> 2;
    #pragma unroll
    for (int j = 0; j < 8; j++) {
      int n = n0 + txn * 8 + j;
      int b = n >> 11, t = n & 2047;
      float4 sv = make_float4(acc[cg * 4 + 0][j] + bxv[cg * 4 + 0],
                              acc[cg * 4 + 1][j] + bxv[cg * 4 + 1],
                              acc[cg * 4 + 2][j] + bxv[cg * 4 + 2],
                              acc[cg * 4 + 3][j] + bxv[cg * 4 + 3]);
      *(float4*)&xout[((size_t)((b << 9) + c)) * 8192 + 4 * t] = sv;
    }
  }
}

// ---------------- RVQ core (proven, unchanged) ----------------
__global__ __launch_bounds__(256) void rvq_kernel(const float* __restrict__ codebooks,
                                                  const float* __restrict__ e0t,
                                                  const float* __restrict__ cbsW,
                                                  const float* __restrict__ ptW,
                                                  const float* __restrict__ beffW,
                                                  float* __restrict__ Qout,
                                                  float* __restrict__ codesOut,
                                                  float* __restrict__ lossPart) {
  __shared__ float cbv[8][1024];
  __shared__ float cbs2[2][1024];
  __shared__ float Pt[36 * 65];
  __shared__ float est[16][72];
  __shared__ float lred[4];
  int tid = threadIdx.x, wid = tid >> 6, lane = tid & 63;
  int nb0 = blockIdx.x * 16;
  for (int idx = tid; idx < 2340; idx += 256) Pt[idx] = ptW[idx];
  for (int idx = tid; idx < 16 * 72; idx += 256)
    est[idx / 72][idx % 72] = e0t[(size_t)nb0 * 72 + idx] + beffW[idx % 72];
  float lossLocal = 0.f;

  for (int i = 0; i < NQ; i++) {
    __syncthreads();
    const float* cbg = codebooks + (size_t)i * CBS * CBD;
    for (int lin = tid; lin < 2048; lin += 256) {
      int j = lin >> 1, half = (lin & 1) << 2;
      float4 v = *(const float4*)(cbg + (size_t)j * 8 + half);
      cbv[half + 0][j] = v.x; cbv[half + 1][j] = v.y;
      cbv[half + 2][j] = v.z; cbv[half + 3][j] = v.w;
    }
    for (int lin = tid; lin < 1024; lin += 256) {
      cbs2[0][lin] = cbsW[((size_t)i * 2 + 0) * 1024 + lin];
      cbs2[1][lin] = cbsW[((size_t)i * 2 + 1) * 1024 + lin];
    }
    __syncthreads();

    float ze[4][8], en[4][8];
    #pragma unroll
    for (int w = 0; w < 4; w++) {
      int tokl = wid * 4 + w;
      float ss = 0.f;
      #pragma unroll
      for (int d = 0; d < 8; d++) { float v = est[tokl][i * 8 + d]; ze[w][d] = v; ss += v * v; }
      float inv = 1.0f / fmaxf(sqrtf(ss), EPSN);
      #pragma unroll
      for (int d = 0; d < 8; d++) en[w][d] = ze[w][d] * inv;
    }
    float best[4]; int bidx[4];
    #pragma unroll
    for (int w = 0; w < 4; w++) { best[w] = -INFINITY; bidx[w] = 0; }
    #pragma unroll 4
    for (int r = 0; r < 16; r++) {
      int j = lane + (r << 6);
      float c0 = cbv[0][j], c1 = cbv[1][j], c2 = cbv[2][j], c3 = cbv[3][j];
      float c4 = cbv[4][j], c5 = cbv[5][j], c6 = cbv[6][j], c7 = cbv[7][j];
      float ti = cbs2[0][j], ns = cbs2[1][j];
      #pragma unroll
      for (int w = 0; w < 4; w++) {
        float dt = en[w][0] * c0;
        dt = fmaf(en[w][1], c1, dt); dt = fmaf(en[w][2], c2, dt);
        dt = fmaf(en[w][3], c3, dt); dt = fmaf(en[w][4], c4, dt);
        dt = fmaf(en[w][5], c5, dt); dt = fmaf(en[w][6], c6, dt);
        dt = fmaf(en[w][7], c7, dt);
        float s = fmaf(dt, ti, -ns);
        if (s > best[w]) { best[w] = s; bidx[w] = j; }
      }
    }
    #pragma unroll
    for (int w = 0; w < 4; w++) {
      #pragma unroll
      for (int off = 32; off; off >>= 1) {
        float so = __shfl_xor(best[w], off);
        int jo = __shfl_xor(bidx[w], off);
        if (so > best[w] || (so == best[w] && jo < bidx[w])) { best[w] = so; bidx[w] = jo; }
      }
    }
    int d = lane & 7;
    #pragma unroll
    for (int w = 0; w < 4; w++) {
      int jstar = bidx[w];
      int tokl = wid * 4 + w;
      int n = nb0 + tokl;
      float qd = cbv[d][jstar];
      float diff = ze[w][d] - qd;
      float sq = diff * diff;
      sq += __shfl_xor(sq, 1); sq += __shfl_xor(sq, 2); sq += __shfl_xor(sq, 4);
      if (lane == 0) lossLocal += sq;
      if (lane < 8) Qout[(size_t)(i * 8 + lane) * NTOK + n] = qd;
      if (lane == 0) codesOut[(size_t)((n >> 11) * NQ + i) * TQ + (n & (TQ - 1))] = (float)jstar;
      if (i < NQ - 1) {
        int f = lane >> 3, d2 = lane & 7;
        int ip = i + 1 + f;
        if (ip < NQ) {
          int tri = (ip * (ip - 1)) / 2 + i;
          const float* prow = &Pt[tri * 65 + d2 * 8];
          float s = 0.f;
          #pragma unroll
          for (int dp = 0; dp < 8; dp++) s = fmaf(prow[dp], cbv[dp][jstar], s);
          est[tokl][ip * 8 + d2] -= s;
        }
      }
    }
  }
  if (lane == 0) lred[wid] = lossLocal;
  __syncthreads();
  if (tid == 0) {
    float s = ((lred[0] + lred[1]) + lred[2]) + lred[3];
    lossPart[blockIdx.x] = s;
  }
}

__global__ void loss_fin(const float* __restrict__ lossPart, float* __restrict__ out) {
  __shared__ float s[256];
  int tid = threadIdx.x;
  float v = 0.f;
  for (int r = 0; r < 4; r++) v += lossPart[tid + r * 256];
  s[tid] = v;
  __syncthreads();
  for (int w = 128; w; w >>= 1) {
    if (tid < w) s[tid] += s[tid + w];
    __syncthreads();
  }
  if (tid == 0) {
    float total = s[0] / 131072.0f;
    out[0] = total;
    out[1] = total;
  }
}

// ---------------- launch ----------------
extern "C" void kernel_launch(void* const* d_in, const int* in_sizes, int n_in,
                              void* d_out, int out_size, void* d_ws, size_t ws_size,
                              hipStream_t stream) {
  const float* z      = (const float*)d_in[0];
  const float* down_w = (const float*)d_in[1];
  const float* down_b = (const float*)d_in[2];
  const float* up_w   = (const float*)d_in[3];
  const float* up_b   = (const float*)d_in[4];
  const float* in_v   = (const float*)d_in[5];
  const float* in_g   = (const float*)d_in[6];
  const float* in_b   = (const float*)d_in[7];
  const float* out_v  = (const float*)d_in[8];
  const float* out_g  = (const float*)d_in[9];
  const float* out_b  = (const float*)d_in[10];
  const float* codebooks = (const float*)d_in[11];
  float* ws = (float*)d_ws;
  float* xout = (float*)d_out;
  float* codesOut = xout + (size_t)8 * 512 * 8192;
  float* lossOut = codesOut + (size_t)8 * NQ * TQ;

  hipLaunchKernelGGL(prep_small1, dim3(458), dim3(256), 0, stream,
                     in_v, in_g, out_v, out_g, out_b, codebooks,
                     down_w, down_b, up_w, up_b, ws);
  hipLaunchKernelGGL(prep2, dim3(594), dim3(256), 0, stream, in_b, out_b, ws);
  hipLaunchKernelGGL((smallmm<0>), dim3(8, 8, 4), dim3(256), 0, stream, down_w, ws + OFF_WD);
  hipLaunchKernelGGL((smallmm<1>), dim3(8, 8, 4), dim3(256), 0, stream, up_w, ws + OFF_WEFF);
  hipLaunchKernelGGL(prep_wdsplit, dim3(4096), dim3(256), 0, stream,
                     ws + OFF_WD, (u16*)(ws + OFF_WDP));
  hipLaunchKernelGGL(prep_wx, dim3(128), dim3(256), 0, stream,
                     ws + OFF_WEFF, ws + OFF_WOUTS, ws + OFF_WX);
  // fused down: x2 = W_d(3-split) @ zg + b_d
  hipLaunchKernelGGL(gemm_down, dim3(128, 4), dim3(256), 0, stream,
                     (const u16*)(ws + OFF_WDP), z, ws + OFF_BD, ws + OFF_X2);
  // e0t = WinN @ x2
  hipLaunchKernelGGL((gemm_conv<1, 1>), dim3(128, 1), dim3(256), 0, stream,
                     ws + OFF_WINN, ws + OFF_X2, (const float*)nullptr, ws + OFF_E0T, 72, 512, 16384, 2048);
  // RVQ
  hipLaunchKernelGGL(rvq_kernel, dim3(1024), dim3(256), 0, stream,
                     codebooks, ws + OFF_E0T, ws + OFF_CBS, ws + OFF_PT, ws + OFF_BEFF,
                     ws + OFF_Q, codesOut, ws + OFF_LOSS);
  // x = Wx @ Q + bx
  hipLaunchKernelGGL(xfin, dim3(128, 16), dim3(256), 0, stream,
                     ws + OFF_WX, ws + OFF_Q, ws + OFF_BUP, xout);
  hipLaunchKernelGGL(loss_fin, dim3(1), dim3(256), 0, stream, ws + OFF_LOSS, lossOut);
}